// Round 8
// baseline (524.097 us; speedup 1.0000x reference)
//
#include <hip/hip_runtime.h>
#include <math.h>

// Problem constants (from reference)
#define NG   1024        // graphs
#define NP   256         // nodes per graph
#define EPG  4096        // edges per graph
#define ETOT 4194304     // total edges
#define NTOT (NG * NP)   // 262144 nodes
#define FIN  7
#define HD   64
#define KC   50
#define SP   50          // ASq stride (f32)
#define SH   52          // f16 S row stride
#define CHK  64          // rows per K2 chunk
#define NCH  4           // chunks per graph
#define FST  72          // f16 LDS row stride in k2 (144 B rows, 16B-aligned)
#define EMAX 3072        // per-half edge staging capacity (avg 2048, 18+ sigma)

// NOTE (R2): __launch_bounds__ 2nd arg acts as CUDA-style min BLOCKS/CU;
// (512,2) => 128-VGPR cap, (512,3) => ~85. Keep per-lane arrays small.
// NOTE (R3): LDS atomic scatter was 1215 us -> counting-sort gather in k1.
// NOTE (R4): persistent per-lane arrays spill at the VGPR cap -> wave-row regs.
// NOTE (R5): GEMV-style phases are latency-bound -> f16 MFMA for k2 GEMMs.
// NOTE (R6): k1 was barrier/atomic bound -> split k1a (dual sort + gather agg)
// and k1b (A^2 chunks at 4096 blocks).
// NOTE (R7): k3 VALU-bound on gather addressing (~9 instr/edge). ->
// premultiplied u16 offsets (di*52), f16 S (3 blocks/CU), 2 blocks/graph.

typedef __attribute__((ext_vector_type(8))) _Float16 v8h;
typedef __attribute__((ext_vector_type(4))) float v4f;

// Inter-kernel intermediates as statics: no hipMalloc, graph-capture safe.
__device__ float g_xagg[NTOT * 8];                  // x+agg, padded to 8
__device__ _Float16 g_Sh[(size_t)NTOT * SH];        // S rows, f16, stride 52
__device__ unsigned short g_sdi16[ETOT];            // di*52 offsets, si-sorted
__device__ unsigned int g_roff[NG * 256];           // exclusive si-row offsets
__device__ float g_PTp[(size_t)NG * NCH * KC * HD]; // xp partials [k][d]
__device__ float g_Gp[(size_t)NG * NCH * KC * KC];  // G partials [k][c]
__device__ float g_Ap2[(size_t)NG * 2 * KC * KC];   // Ap half-partials [k][c]

__global__ void zero_ws(float* ws) {
    if (threadIdx.x < 4) ws[threadIdx.x] = 0.f;
}

// ws[0]=sumA2, ws[1]=sum S logS, ws[2]=trace(Ap)=sum(A.SSt), ws[3]=||G||^2
__global__ void finalize_k(const float* __restrict__ ws, float* __restrict__ out) {
    if (threadIdx.x == 0) {
        float num = ws[0] - 2.f * ws[2] + ws[3];
        float link = sqrtf(fmaxf(num, 0.f)) / 67108864.0f;   // / (B*n*n)
        float ent  = -ws[1] / 262144.0f;                     // / N
        out[2048] = link + ent;
    }
}

__device__ __forceinline__ float blockReduceN(float v, float* red, int nw) {
    __syncthreads();
    #pragma unroll
    for (int o = 32; o > 0; o >>= 1) v += __shfl_down(v, o);
    if ((threadIdx.x & 63) == 0) red[threadIdx.x >> 6] = v;
    __syncthreads();
    float r = 0.f;
    if (threadIdx.x == 0) {
        for (int i = 0; i < nw; ++i) r += red[i];
    }
    return r;
}

// ---- K1a: dual counting sort (si->di*52 for k3, di->si for agg) + gather agg
// LDS ~36 KB -> 3 blocks/CU
__launch_bounds__(512, 3)
__global__ void k1a_sort(const int* __restrict__ esrc, const int* __restrict__ edst,
                         const float* __restrict__ x)
{
    __shared__ unsigned short cells[EPG];       // 8 KB
    __shared__ unsigned short sdi16[EPG];       // 8 KB  (si-sorted di*52)
    __shared__ unsigned char ssi[EPG];          // 4 KB  (di-sorted si)
    __shared__ float xt8[NP * 8];               // 8 KB  (x, stride 8, pad 0)
    __shared__ unsigned int hist_si[256], roff_si[256], cur_si[256];
    __shared__ unsigned int hist_di[256], cur_di[256];
    __shared__ unsigned int roff_di[NP + 1];

    const int g = blockIdx.x, tid = threadIdx.x;
    const int lane = tid & 63, wid = tid >> 6;

    if (tid < 256) { hist_si[tid] = 0u; hist_di[tid] = 0u; }
    __syncthreads();

    for (int e = tid; e < EPG; e += 512) {
        int s = esrc[g * EPG + e] & (NP - 1);
        int d = edst[g * EPG + e] & (NP - 1);
        cells[e] = (unsigned short)((s << 8) | d);
        atomicAdd(&hist_si[s], 1u);
        atomicAdd(&hist_di[d], 1u);
    }
    for (int i = tid; i < NP * 8; i += 512) {
        int n = i >> 3, f = i & 7;
        xt8[i] = (f < FIN) ? x[g * NP * FIN + n * FIN + f] : 0.f;
    }
    __syncthreads();

    // parallel exclusive scans: wave 0 -> si, wave 1 -> di
    if (wid == 0) {
        unsigned carry = 0;
        for (int c = 0; c < 4; ++c) {
            unsigned v = hist_si[c * 64 + lane];
            unsigned s = v;
            #pragma unroll
            for (int o = 1; o < 64; o <<= 1) {
                unsigned t = __shfl_up(s, o);
                if (lane >= o) s += t;
            }
            unsigned excl = s - v + carry;
            roff_si[c * 64 + lane] = excl;
            cur_si[c * 64 + lane] = excl;
            carry += __shfl(s, 63);
        }
    } else if (wid == 1) {
        unsigned carry = 0;
        for (int c = 0; c < 4; ++c) {
            unsigned v = hist_di[c * 64 + lane];
            unsigned s = v;
            #pragma unroll
            for (int o = 1; o < 64; o <<= 1) {
                unsigned t = __shfl_up(s, o);
                if (lane >= o) s += t;
            }
            unsigned excl = s - v + carry;
            roff_di[c * 64 + lane] = excl;
            cur_di[c * 64 + lane] = excl;
            carry += __shfl(s, 63);
        }
        if (lane == 0) roff_di[NP] = EPG;
    }
    __syncthreads();

    // placement for both sorts (sdi stored as premultiplied di*SH)
    for (int e = tid; e < EPG; e += 512) {
        int c = cells[e]; int si = c >> 8, di = c & 255;
        unsigned p1 = atomicAdd(&cur_si[si], 1u);
        sdi16[p1] = (unsigned short)(di * SH);
        unsigned p2 = atomicAdd(&cur_di[di], 1u);
        ssi[p2] = (unsigned char)si;
    }
    __syncthreads();

    // persist si-sorted offset list + row offsets for k3
    for (int i = tid; i < EPG / 2; i += 512)
        ((unsigned int*)g_sdi16)[g * (EPG / 2) + i] = ((const unsigned int*)sdi16)[i];
    if (tid < 256) g_roff[g * 256 + tid] = roff_si[tid];

    // gather agg: 8 lanes per node (f = lane&7), write x+agg
    {
        const int gidx = tid >> 3, f = tid & 7;
        for (int n = gidx; n < NP; n += 64) {
            int beg = roff_di[n], end = roff_di[n + 1];
            float a = xt8[n * 8 + f];
            for (int e = beg; e < end; ++e)
                a += xt8[ssi[e] * 8 + f];
            g_xagg[g * NP * 8 + n * 8 + f] = a;
        }
    }
}

// ---- K1b: sum(A^2) dense counts, 4 blocks per graph (parallel chunks) -------
__launch_bounds__(512, 2)
__global__ void k1b_a2(const int* __restrict__ esrc, const int* __restrict__ edst,
                       float* __restrict__ ws)
{
    __shared__ unsigned int cnt[8192];          // 32 KB (two u16 counters / word)
    __shared__ float red[8];

    const int g = blockIdx.x >> 2, ch = blockIdx.x & 3, tid = threadIdx.x;

    for (int i = tid; i < 8192; i += 512) cnt[i] = 0u;
    __syncthreads();

    int base = ch << 14;
    for (int e = tid; e < EPG; e += 512) {
        int s = esrc[g * EPG + e] & (NP - 1);
        int d = edst[g * EPG + e] & (NP - 1);
        int r = ((s << 8) | d) - base;
        if ((unsigned)r < 16384u)
            atomicAdd(&cnt[r >> 1], (r & 1) ? 0x10000u : 1u);
    }
    __syncthreads();

    float sumA2 = 0.f;
    for (int i = tid; i < 8192; i += 512) {
        unsigned v = cnt[i];
        float m0 = (float)(v & 0xffffu), m1 = (float)(v >> 16);
        sumA2 += m0 * m0 + m1 * m1;
    }

    float r = blockReduceN(sumA2, red, 8);
    if (tid == 0) atomicAdd(&ws[0], r);
}

// ---- K2: MFMA f16 — MLP1, h-GEMM, P-GEMM, softmax, xp/G-GEMMs ---------------
__launch_bounds__(512, 2)
__global__ void k2_mlp(const float* __restrict__ W1a, const float* __restrict__ b1a,
                       const float* __restrict__ W1b, const float* __restrict__ b1b,
                       const float* __restrict__ Wp,  const float* __restrict__ bp,
                       float* __restrict__ ws)
{
    __shared__ __align__(16) float xt[CHK * 8];          // 2 KB
    __shared__ __align__(16) _Float16 t1b[CHK * FST];    // 9.2 KB  t1   [n][j]
    __shared__ __align__(16) _Float16 W1bT[HD * FST];    // 9.2 KB  W1b^T[d][j]
    __shared__ __align__(16) _Float16 WpT[HD * FST];     // 9.2 KB  Wp^T [k][d]
    __shared__ __align__(16) _Float16 hN[CHK * FST];     // 9.2 KB  h    [n][d]
    __shared__ __align__(16) _Float16 hT[HD * FST];      // 9.2 KB  h^T  [d][n]
    __shared__ __align__(16) _Float16 StT[HD * FST];     // 9.2 KB  S^T  [k][n]
    __shared__ __align__(16) float Pf[CHK * 66];         // 16.9 KB P    [n][k]
    __shared__ float red[8];

    const int b = blockIdx.x, rbase = b * CHK, tid = threadIdx.x;
    const int lane = tid & 63, wid = tid >> 6;
    const int l15 = lane & 15, quad = lane >> 4;
    const int fko = quad * 8;

    xt[tid] = g_xagg[rbase * 8 + tid];
    for (int i = tid; i < HD * HD; i += 512) {
        int j = i >> 6, d = i & 63;
        W1bT[d * FST + j] = (_Float16)W1b[i];
    }
    for (int i = tid; i < HD * KC; i += 512) {
        int d = i / KC, k = i - d * KC;
        WpT[k * FST + d] = (_Float16)Wp[i];
    }
    __syncthreads();

    // t1 = relu((x+agg) @ W1a + b1a)
    {
        float w1r[FIN];
        #pragma unroll
        for (int f = 0; f < FIN; ++f) w1r[f] = W1a[f * HD + lane];
        float br = b1a[lane];
        for (int n = wid; n < CHK; n += 8) {
            float a = br;
            #pragma unroll
            for (int f = 0; f < FIN; ++f) a += xt[n * 8 + f] * w1r[f];
            t1b[n * FST + lane] = (_Float16)fmaxf(a, 0.f);
        }
    }
    __syncthreads();

    // h = t1 @ W1b + b1b
    for (int t = wid * 2; t < wid * 2 + 2; ++t) {
        int mt = (t >> 2) << 4, nt = (t & 3) << 4;
        v4f acc = {0.f, 0.f, 0.f, 0.f};
        #pragma unroll
        for (int ks = 0; ks < 2; ++ks) {
            v8h af = *(const v8h*)&t1b[(mt + l15) * FST + ks * 32 + fko];
            v8h bf = *(const v8h*)&W1bT[(nt + l15) * FST + ks * 32 + fko];
            acc = __builtin_amdgcn_mfma_f32_16x16x32_f16(af, bf, acc, 0, 0, 0);
        }
        int d = nt + l15;
        float bv = b1b[d];
        #pragma unroll
        for (int r = 0; r < 4; ++r) {
            int m = mt + quad * 4 + r;
            _Float16 hv = (_Float16)(acc[r] + bv);
            hN[m * FST + d] = hv;
            hT[d * FST + m] = hv;
        }
    }
    __syncthreads();

    // P = h @ Wp + bp
    for (int t = wid * 2; t < wid * 2 + 2; ++t) {
        int mt = (t >> 2) << 4, nt = (t & 3) << 4;
        v4f acc = {0.f, 0.f, 0.f, 0.f};
        #pragma unroll
        for (int ks = 0; ks < 2; ++ks) {
            v8h af = *(const v8h*)&hN[(mt + l15) * FST + ks * 32 + fko];
            v8h bf = *(const v8h*)&WpT[(nt + l15) * FST + ks * 32 + fko];
            acc = __builtin_amdgcn_mfma_f32_16x16x32_f16(af, bf, acc, 0, 0, 0);
        }
        int kcol = nt + l15;
        if (kcol < KC) {
            float bv = bp[kcol];
            #pragma unroll
            for (int r = 0; r < 4; ++r)
                Pf[(mt + quad * 4 + r) * 66 + kcol] = acc[r] + bv;
        }
    }
    __syncthreads();

    // softmax -> StT f16, g_Sh f16 (stride 52, pads 0), entropy partial
    float entL = 0.f;
    for (int n = wid; n < CHK; n += 8) {
        float a = (lane < KC) ? Pf[n * 66 + lane] : -INFINITY;
        float m = a;
        #pragma unroll
        for (int o = 32; o > 0; o >>= 1) m = fmaxf(m, __shfl_xor(m, o));
        float e = expf(a - m);
        float ss = e;
        #pragma unroll
        for (int o = 32; o > 0; o >>= 1) ss += __shfl_xor(ss, o);
        float s = e / ss;
        if (lane < KC) {
            StT[lane * FST + n] = (_Float16)s;
            entL += s * logf(s + 1e-15f);
        }
        if (lane < SH)
            g_Sh[(size_t)(rbase + n) * SH + lane] = (_Float16)((lane < KC) ? s : 0.f);
    }
    __syncthreads();

    // xp = S^T h ; G = S^T S (fused, shared A-frag)
    for (int t = wid * 2; t < wid * 2 + 2; ++t) {
        int mt = (t >> 2) << 4, nt = (t & 3) << 4;
        v4f axp = {0.f, 0.f, 0.f, 0.f};
        v4f ag  = {0.f, 0.f, 0.f, 0.f};
        #pragma unroll
        for (int ks = 0; ks < 2; ++ks) {
            v8h af = *(const v8h*)&StT[(mt + l15) * FST + ks * 32 + fko];
            v8h bh = *(const v8h*)&hT[(nt + l15) * FST + ks * 32 + fko];
            v8h bs = *(const v8h*)&StT[(nt + l15) * FST + ks * 32 + fko];
            axp = __builtin_amdgcn_mfma_f32_16x16x32_f16(af, bh, axp, 0, 0, 0);
            ag  = __builtin_amdgcn_mfma_f32_16x16x32_f16(af, bs, ag, 0, 0, 0);
        }
        int col = nt + l15;
        #pragma unroll
        for (int r = 0; r < 4; ++r) {
            int row = mt + quad * 4 + r;
            if (row < KC) {
                g_PTp[(size_t)b * (KC * HD) + row * HD + col] = axp[r];
                if (col < KC)
                    g_Gp[(size_t)b * (KC * KC) + row * KC + col] = ag[r];
            }
        }
    }

    float r = blockReduceN(entL, red, 8);
    if (tid == 0) atomicAdd(&ws[1], r);
}

// ---- K3: AS gather (premult u16 offsets, f16 S) + wave-row Ap + trace -------
// 2 blocks per graph (128 rows each). LDS ~46 KB -> 3 blocks/CU.
__launch_bounds__(512, 3)
__global__ void k3_as(float* __restrict__ ws)
{
    __shared__ __align__(16) _Float16 St[NP * SH];    // 26.6 KB, full graph
    __shared__ __align__(16) float ASq[64 * SP];      // 12.5 KB (64-row slab)
    __shared__ unsigned short eoff[EMAX];             // 6 KB
    __shared__ unsigned int roffL[129];
    __shared__ float red[8];

    const int g = blockIdx.x >> 1, half = blockIdx.x & 1, tid = threadIdx.x;
    const int lane = tid & 63, wid = tid >> 6;
    const int cc = (lane < SP) ? lane : (SP - 1);

    // uniform edge range for this half (scalar loads)
    const unsigned beg = g_roff[g * 256 + half * 128];
    const unsigned end = half ? (unsigned)EPG : g_roff[g * 256 + 128];
    const int cnt = (int)(end - beg);

    // stage full-graph f16 S (u32 copies; 256*52*2 B = 26.6 KB)
    for (int i = tid; i < NP * SH / 2; i += 512)
        ((unsigned int*)St)[i] =
            ((const unsigned int*)(g_Sh + (size_t)g * NP * SH))[i];
    // stage this half's premultiplied edge offsets
    for (int e = tid; e < cnt && e < EMAX; e += 512)
        eoff[e] = g_sdi16[(size_t)g * EPG + beg + e];
    // row offsets for the 128 rows (+ terminator)
    if (tid < 128) roffL[tid] = g_roff[g * 256 + half * 128 + tid];
    if (tid == 128) roffL[128] = end;
    __syncthreads();

    float ap[7];
    #pragma unroll
    for (int j = 0; j < 7; ++j) ap[j] = 0.f;
    const _Float16* Stc = St + cc;    // lane-column base

    for (int q = 0; q < 2; ++q) {
        // gather 64-row slab: AS[n,c] = sum_{e in row} S[di_e, c]
        for (int rr = wid * 8; rr < wid * 8 + 8; ++rr) {
            int rloc = q * 64 + rr;
            int b0 = (int)(roffL[rloc] - beg), e1 = (int)(roffL[rloc + 1] - beg);
            if (e1 > EMAX) e1 = EMAX;
            float acc = 0.f;
            int e = b0;
            for (; e + 4 <= e1; e += 4) {
                float a0 = (float)Stc[eoff[e]];
                float a1 = (float)Stc[eoff[e + 1]];
                float a2 = (float)Stc[eoff[e + 2]];
                float a3 = (float)Stc[eoff[e + 3]];
                acc += (a0 + a1) + (a2 + a3);
            }
            for (; e < e1; ++e) acc += (float)Stc[eoff[e]];
            if (lane < SP) ASq[rr * SP + lane] = acc;
        }
        __syncthreads();

        // Ap[k,c] += sum_n S[n,k]*AS[n,c]; wave w owns k = w + 8j
        for (int n = 0; n < 64; ++n) {
            float as = ASq[n * SP + cc];
            const _Float16* sr = &St[(half * 128 + q * 64 + n) * SH];
            #pragma unroll
            for (int j = 0; j < 7; ++j) {
                int k = wid + j * 8;
                int kcl = (k < SP) ? k : (SP - 1);
                ap[j] += (float)sr[kcl] * as;       // wave-uniform bcast
            }
        }
        __syncthreads();    // before next slab overwrites ASq
    }

    // write Ap half-partial; trace accumulates sum(A .* SSt)
    float tr = 0.f;
    #pragma unroll
    for (int j = 0; j < 7; ++j) {
        int k = wid + j * 8;
        if (k < SP && lane < SP) {
            g_Ap2[(size_t)blockIdx.x * (KC * KC) + k * KC + lane] = ap[j];
            if (lane == k) tr += ap[j];
        }
    }

    float r = blockReduceN(tr, red, 8);
    if (tid == 0) atomicAdd(&ws[2], r);
}

// ---- K4: combine partials, ||G||^2, dense GIN, classifier -------------------
__launch_bounds__(256, 3)
__global__ void k4_head(const float* __restrict__ W2a, const float* __restrict__ b2a,
                        const float* __restrict__ W2b, const float* __restrict__ b2b,
                        const float* __restrict__ Wl,  const float* __restrict__ bl,
                        float* __restrict__ out, float* __restrict__ ws)
{
    __shared__ __align__(16) float xpL[KC * HD];    // 12.8 KB  xp [k][d]
    __shared__ __align__(16) float Ap[KC * KC];     // 10 KB
    __shared__ __align__(16) float h2[KC * HD];     // 12.8 KB
    __shared__ __align__(16) float tt[KC * HD];     // 12.8 KB
    __shared__ float red[4];

    const int g = blockIdx.x, tid = threadIdx.x;
    const int lane = tid & 63, wid = tid >> 6;

    for (int i = tid; i < KC * HD; i += 256) {
        float v = 0.f;
        #pragma unroll
        for (int c = 0; c < NCH; ++c)
            v += g_PTp[(size_t)(g * NCH + c) * (KC * HD) + i];
        xpL[i] = v;
    }
    float sumG2 = 0.f;
    for (int i = tid; i < KC * KC; i += 256) {
        float v = 0.f;
        #pragma unroll
        for (int c = 0; c < NCH; ++c)
            v += g_Gp[(size_t)(g * NCH + c) * (KC * KC) + i];
        sumG2 += v * v;
        Ap[i] = g_Ap2[(size_t)(g * 2) * (KC * KC) + i]
              + g_Ap2[(size_t)(g * 2 + 1) * (KC * KC) + i];
    }
    __syncthreads();

    // h2[k][d] = xp[k][d] + sum_l Ap[k][l] * xp[l][d]
    for (int k = wid; k < KC; k += 4) {
        float a = xpL[k * HD + lane];
        #pragma unroll
        for (int l = 0; l < KC; ++l)
            a += Ap[k * KC + l] * xpL[l * HD + lane];
        h2[k * HD + lane] = a;
    }
    __syncthreads();

    // t = relu(h2 @ W2a + b2a)
    {
        float wr[HD];
        #pragma unroll
        for (int d = 0; d < HD; ++d) wr[d] = W2a[d * HD + lane];
        float br = b2a[lane];
        for (int k = wid; k < KC; k += 4) {
            float a0 = br, a1 = 0.f, a2 = 0.f, a3 = 0.f;
            const float4* h4 = (const float4*)&h2[k * HD];
            #pragma unroll
            for (int i = 0; i < 16; ++i) {
                float4 v = h4[i];
                a0 += v.x * wr[4*i]; a1 += v.y * wr[4*i+1];
                a2 += v.z * wr[4*i+2]; a3 += v.w * wr[4*i+3];
            }
            tt[k * HD + lane] = fmaxf((a0 + a1) + (a2 + a3), 0.f);
        }
    }
    __syncthreads();

    // h3 = t @ W2b + b2b; fold mean over k and Wl into logits partials
    float l0 = 0.f, l1 = 0.f;
    {
        float wr[HD];
        #pragma unroll
        for (int j = 0; j < HD; ++j) wr[j] = W2b[j * HD + lane];
        float br = b2b[lane];
        float wl0 = Wl[lane * 2], wl1 = Wl[lane * 2 + 1];
        for (int k = wid; k < KC; k += 4) {
            float a0 = br, a1 = 0.f, a2 = 0.f, a3 = 0.f;
            const float4* t4 = (const float4*)&tt[k * HD];
            #pragma unroll
            for (int i = 0; i < 16; ++i) {
                float4 v = t4[i];
                a0 += v.x * wr[4*i]; a1 += v.y * wr[4*i+1];
                a2 += v.z * wr[4*i+2]; a3 += v.w * wr[4*i+3];
            }
            float a = (a0 + a1) + (a2 + a3);
            l0 += a * wl0; l1 += a * wl1;
        }
    }

    float rG2 = blockReduceN(sumG2, red, 4);
    float rl0 = blockReduceN(l0, red, 4);
    float rl1 = blockReduceN(l1, red, 4);
    if (tid == 0) {
        atomicAdd(&ws[3], rG2);
        float g0 = bl[0] + rl0 * (1.f / KC);
        float g1 = bl[1] + rl1 * (1.f / KC);
        float mm = fmaxf(g0, g1);
        float lse = mm + logf(expf(g0 - mm) + expf(g1 - mm));
        out[2 * g]     = g0 - lse;
        out[2 * g + 1] = g1 - lse;
    }
}

extern "C" void kernel_launch(void* const* d_in, const int* in_sizes, int n_in,
                              void* d_out, int out_size, void* d_ws, size_t ws_size,
                              hipStream_t stream) {
    const float* x    = (const float*)d_in[0];
    const float* W1a  = (const float*)d_in[1];
    const float* b1a  = (const float*)d_in[2];
    const float* W1b  = (const float*)d_in[3];
    const float* b1b  = (const float*)d_in[4];
    const float* Wp   = (const float*)d_in[5];
    const float* bp   = (const float*)d_in[6];
    const float* W2a  = (const float*)d_in[7];
    const float* b2a  = (const float*)d_in[8];
    const float* W2b  = (const float*)d_in[9];
    const float* b2b  = (const float*)d_in[10];
    const float* Wl   = (const float*)d_in[11];
    const float* bl   = (const float*)d_in[12];
    const int*   eidx = (const int*)d_in[13];   // [2, E] int32
    float* out = (float*)d_out;
    float* ws  = (float*)d_ws;

    zero_ws<<<1, 64, 0, stream>>>(ws);
    k1a_sort<<<NG, 512, 0, stream>>>(eidx, eidx + ETOT, x);
    k1b_a2<<<NG * 4, 512, 0, stream>>>(eidx, eidx + ETOT, ws);
    k2_mlp<<<NG * NCH, 512, 0, stream>>>(W1a, b1a, W1b, b1b, Wp, bp, ws);
    k3_as<<<NG * 2, 512, 0, stream>>>(ws);
    k4_head<<<NG, 256, 0, stream>>>(W2a, b2a, W2b, b2b, Wl, bl, out, ws);
    finalize_k<<<1, 64, 0, stream>>>(ws, out);
}

// Round 9
// 478.603 us; speedup vs baseline: 1.0951x; 1.0951x over previous
//
#include <hip/hip_runtime.h>
#include <math.h>

// Problem constants (from reference)
#define NG   1024        // graphs
#define NP   256         // nodes per graph
#define EPG  4096        // edges per graph
#define ETOT 4194304     // total edges
#define NTOT (NG * NP)   // 262144 nodes
#define FIN  7
#define HD   64
#define KC   50
#define SP   50          // packed row stride for g_S / k3 (fp32)
#define CHK  64          // rows per K2 chunk
#define NCH  4           // chunks per graph
#define FST  72          // f16 LDS row stride in k2 (144 B rows, 16B-aligned)

// NOTE (R2): __launch_bounds__ 2nd arg acts as CUDA-style min BLOCKS/CU;
// (512,2) => 128-VGPR cap, (512,3) => ~85. Keep per-lane arrays small.
// NOTE (R3): LDS atomic scatter was 1215 us -> counting-sort gather in k1.
// NOTE (R4): persistent per-lane arrays spill at the VGPR cap -> wave-row regs.
// NOTE (R5): GEMV-style phases are latency-bound -> f16 MFMA for k2 GEMMs.
// NOTE (R6): k1 was barrier/atomic bound -> split k1a/k1b.
// NOTE (R8): f16 S + premult u16 offsets REGRESSED k3 (162->185): +1 cvt per
// gathered element, duplicated staging. k3 is LDS-PIPE bound, not VALU.
// -> R9: fp32 S, offsets read from GLOBAL via scalar loads (readfirstlane'd
// bounds => s_load; byte extract on SALU) — offset stream leaves the LDS pipe.

typedef __attribute__((ext_vector_type(8))) _Float16 v8h;
typedef __attribute__((ext_vector_type(4))) float v4f;

// Inter-kernel intermediates as statics: no hipMalloc, graph-capture safe.
__device__ float g_xagg[NTOT * 8];                  // x+agg, padded to 8
__device__ float g_S[(size_t)NTOT * SP];            // S rows, fp32, packed 50
__device__ unsigned int g_sdi32[ETOT / 4];          // packed u8 di's, si-sorted
__device__ unsigned int g_roff[NG * 256];           // exclusive si-row offsets
__device__ float g_PTp[(size_t)NG * NCH * KC * HD]; // xp partials [k][d]
__device__ float g_Gp[(size_t)NG * NCH * KC * KC];  // G partials [k][c]
__device__ float g_Ap[(size_t)NG * KC * KC];        // Ap [k][c]

__global__ void zero_ws(float* ws) {
    if (threadIdx.x < 4) ws[threadIdx.x] = 0.f;
}

// ws[0]=sumA2, ws[1]=sum S logS, ws[2]=trace(Ap)=sum(A.SSt), ws[3]=||G||^2
__global__ void finalize_k(const float* __restrict__ ws, float* __restrict__ out) {
    if (threadIdx.x == 0) {
        float num = ws[0] - 2.f * ws[2] + ws[3];
        float link = sqrtf(fmaxf(num, 0.f)) / 67108864.0f;   // / (B*n*n)
        float ent  = -ws[1] / 262144.0f;                     // / N
        out[2048] = link + ent;
    }
}

__device__ __forceinline__ float blockReduceN(float v, float* red, int nw) {
    __syncthreads();
    #pragma unroll
    for (int o = 32; o > 0; o >>= 1) v += __shfl_down(v, o);
    if ((threadIdx.x & 63) == 0) red[threadIdx.x >> 6] = v;
    __syncthreads();
    float r = 0.f;
    if (threadIdx.x == 0) {
        for (int i = 0; i < nw; ++i) r += red[i];
    }
    return r;
}

// ---- K1a: dual counting sort (si->di for k3, di->si for agg) + gather agg ---
// LDS ~31 KB -> 3 blocks/CU
__launch_bounds__(512, 3)
__global__ void k1a_sort(const int* __restrict__ esrc, const int* __restrict__ edst,
                         const float* __restrict__ x)
{
    __shared__ unsigned short cells[EPG];       // 8 KB
    __shared__ unsigned char sdi[EPG];          // 4 KB  (si-sorted di)
    __shared__ unsigned char ssi[EPG];          // 4 KB  (di-sorted si)
    __shared__ float xt8[NP * 8];               // 8 KB  (x, stride 8, pad 0)
    __shared__ unsigned int hist_si[256], roff_si[256], cur_si[256];
    __shared__ unsigned int hist_di[256], cur_di[256];
    __shared__ unsigned int roff_di[NP + 1];

    const int g = blockIdx.x, tid = threadIdx.x;
    const int lane = tid & 63, wid = tid >> 6;

    if (tid < 256) { hist_si[tid] = 0u; hist_di[tid] = 0u; }
    __syncthreads();

    for (int e = tid; e < EPG; e += 512) {
        int s = esrc[g * EPG + e] & (NP - 1);
        int d = edst[g * EPG + e] & (NP - 1);
        cells[e] = (unsigned short)((s << 8) | d);
        atomicAdd(&hist_si[s], 1u);
        atomicAdd(&hist_di[d], 1u);
    }
    for (int i = tid; i < NP * 8; i += 512) {
        int n = i >> 3, f = i & 7;
        xt8[i] = (f < FIN) ? x[g * NP * FIN + n * FIN + f] : 0.f;
    }
    __syncthreads();

    // parallel exclusive scans: wave 0 -> si, wave 1 -> di
    if (wid == 0) {
        unsigned carry = 0;
        for (int c = 0; c < 4; ++c) {
            unsigned v = hist_si[c * 64 + lane];
            unsigned s = v;
            #pragma unroll
            for (int o = 1; o < 64; o <<= 1) {
                unsigned t = __shfl_up(s, o);
                if (lane >= o) s += t;
            }
            unsigned excl = s - v + carry;
            roff_si[c * 64 + lane] = excl;
            cur_si[c * 64 + lane] = excl;
            carry += __shfl(s, 63);
        }
    } else if (wid == 1) {
        unsigned carry = 0;
        for (int c = 0; c < 4; ++c) {
            unsigned v = hist_di[c * 64 + lane];
            unsigned s = v;
            #pragma unroll
            for (int o = 1; o < 64; o <<= 1) {
                unsigned t = __shfl_up(s, o);
                if (lane >= o) s += t;
            }
            unsigned excl = s - v + carry;
            roff_di[c * 64 + lane] = excl;
            cur_di[c * 64 + lane] = excl;
            carry += __shfl(s, 63);
        }
        if (lane == 0) roff_di[NP] = EPG;
    }
    __syncthreads();

    // placement for both sorts
    for (int e = tid; e < EPG; e += 512) {
        int c = cells[e]; int si = c >> 8, di = c & 255;
        unsigned p1 = atomicAdd(&cur_si[si], 1u);
        sdi[p1] = (unsigned char)di;
        unsigned p2 = atomicAdd(&cur_di[di], 1u);
        ssi[p2] = (unsigned char)si;
    }
    __syncthreads();

    // persist si-sorted list (packed u32) + row offsets for k3
    for (int i = tid; i < EPG / 4; i += 512)
        g_sdi32[g * (EPG / 4) + i] = ((const unsigned int*)sdi)[i];
    if (tid < 256) g_roff[g * 256 + tid] = roff_si[tid];

    // gather agg: 8 lanes per node (f = lane&7), write x+agg
    {
        const int gidx = tid >> 3, f = tid & 7;
        for (int n = gidx; n < NP; n += 64) {
            int beg = roff_di[n], end = roff_di[n + 1];
            float a = xt8[n * 8 + f];
            for (int e = beg; e < end; ++e)
                a += xt8[ssi[e] * 8 + f];
            g_xagg[g * NP * 8 + n * 8 + f] = a;
        }
    }
}

// ---- K1b: sum(A^2) dense counts, 4 blocks per graph (parallel chunks) -------
__launch_bounds__(512, 2)
__global__ void k1b_a2(const int* __restrict__ esrc, const int* __restrict__ edst,
                       float* __restrict__ ws)
{
    __shared__ unsigned int cnt[8192];          // 32 KB (two u16 counters / word)
    __shared__ float red[8];

    const int g = blockIdx.x >> 2, ch = blockIdx.x & 3, tid = threadIdx.x;

    for (int i = tid; i < 8192; i += 512) cnt[i] = 0u;
    __syncthreads();

    int base = ch << 14;
    for (int e = tid; e < EPG; e += 512) {
        int s = esrc[g * EPG + e] & (NP - 1);
        int d = edst[g * EPG + e] & (NP - 1);
        int r = ((s << 8) | d) - base;
        if ((unsigned)r < 16384u)
            atomicAdd(&cnt[r >> 1], (r & 1) ? 0x10000u : 1u);
    }
    __syncthreads();

    float sumA2 = 0.f;
    for (int i = tid; i < 8192; i += 512) {
        unsigned v = cnt[i];
        float m0 = (float)(v & 0xffffu), m1 = (float)(v >> 16);
        sumA2 += m0 * m0 + m1 * m1;
    }

    float r = blockReduceN(sumA2, red, 8);
    if (tid == 0) atomicAdd(&ws[0], r);
}

// ---- K2: MFMA f16 — MLP1, h-GEMM, P-GEMM, softmax, xp/G-GEMMs ---------------
__launch_bounds__(512, 2)
__global__ void k2_mlp(const float* __restrict__ W1a, const float* __restrict__ b1a,
                       const float* __restrict__ W1b, const float* __restrict__ b1b,
                       const float* __restrict__ Wp,  const float* __restrict__ bp,
                       float* __restrict__ ws)
{
    __shared__ __align__(16) float xt[CHK * 8];          // 2 KB
    __shared__ __align__(16) _Float16 t1b[CHK * FST];    // 9.2 KB  t1   [n][j]
    __shared__ __align__(16) _Float16 W1bT[HD * FST];    // 9.2 KB  W1b^T[d][j]
    __shared__ __align__(16) _Float16 WpT[HD * FST];     // 9.2 KB  Wp^T [k][d]
    __shared__ __align__(16) _Float16 hN[CHK * FST];     // 9.2 KB  h    [n][d]
    __shared__ __align__(16) _Float16 hT[HD * FST];      // 9.2 KB  h^T  [d][n]
    __shared__ __align__(16) _Float16 StT[HD * FST];     // 9.2 KB  S^T  [k][n]
    __shared__ __align__(16) float Pf[CHK * 66];         // 16.9 KB P    [n][k]
    __shared__ float red[8];

    const int b = blockIdx.x, rbase = b * CHK, tid = threadIdx.x;
    const int lane = tid & 63, wid = tid >> 6;
    const int l15 = lane & 15, quad = lane >> 4;
    const int fko = quad * 8;

    xt[tid] = g_xagg[rbase * 8 + tid];
    for (int i = tid; i < HD * HD; i += 512) {
        int j = i >> 6, d = i & 63;
        W1bT[d * FST + j] = (_Float16)W1b[i];
    }
    for (int i = tid; i < HD * KC; i += 512) {
        int d = i / KC, k = i - d * KC;
        WpT[k * FST + d] = (_Float16)Wp[i];
    }
    __syncthreads();

    // t1 = relu((x+agg) @ W1a + b1a)
    {
        float w1r[FIN];
        #pragma unroll
        for (int f = 0; f < FIN; ++f) w1r[f] = W1a[f * HD + lane];
        float br = b1a[lane];
        for (int n = wid; n < CHK; n += 8) {
            float a = br;
            #pragma unroll
            for (int f = 0; f < FIN; ++f) a += xt[n * 8 + f] * w1r[f];
            t1b[n * FST + lane] = (_Float16)fmaxf(a, 0.f);
        }
    }
    __syncthreads();

    // h = t1 @ W1b + b1b
    for (int t = wid * 2; t < wid * 2 + 2; ++t) {
        int mt = (t >> 2) << 4, nt = (t & 3) << 4;
        v4f acc = {0.f, 0.f, 0.f, 0.f};
        #pragma unroll
        for (int ks = 0; ks < 2; ++ks) {
            v8h af = *(const v8h*)&t1b[(mt + l15) * FST + ks * 32 + fko];
            v8h bf = *(const v8h*)&W1bT[(nt + l15) * FST + ks * 32 + fko];
            acc = __builtin_amdgcn_mfma_f32_16x16x32_f16(af, bf, acc, 0, 0, 0);
        }
        int d = nt + l15;
        float bv = b1b[d];
        #pragma unroll
        for (int r = 0; r < 4; ++r) {
            int m = mt + quad * 4 + r;
            _Float16 hv = (_Float16)(acc[r] + bv);
            hN[m * FST + d] = hv;
            hT[d * FST + m] = hv;
        }
    }
    __syncthreads();

    // P = h @ Wp + bp
    for (int t = wid * 2; t < wid * 2 + 2; ++t) {
        int mt = (t >> 2) << 4, nt = (t & 3) << 4;
        v4f acc = {0.f, 0.f, 0.f, 0.f};
        #pragma unroll
        for (int ks = 0; ks < 2; ++ks) {
            v8h af = *(const v8h*)&hN[(mt + l15) * FST + ks * 32 + fko];
            v8h bf = *(const v8h*)&WpT[(nt + l15) * FST + ks * 32 + fko];
            acc = __builtin_amdgcn_mfma_f32_16x16x32_f16(af, bf, acc, 0, 0, 0);
        }
        int kcol = nt + l15;
        if (kcol < KC) {
            float bv = bp[kcol];
            #pragma unroll
            for (int r = 0; r < 4; ++r)
                Pf[(mt + quad * 4 + r) * 66 + kcol] = acc[r] + bv;
        }
    }
    __syncthreads();

    // softmax -> StT f16, g_S fp32 (packed 50), entropy partial
    float entL = 0.f;
    for (int n = wid; n < CHK; n += 8) {
        float a = (lane < KC) ? Pf[n * 66 + lane] : -INFINITY;
        float m = a;
        #pragma unroll
        for (int o = 32; o > 0; o >>= 1) m = fmaxf(m, __shfl_xor(m, o));
        float e = expf(a - m);
        float ss = e;
        #pragma unroll
        for (int o = 32; o > 0; o >>= 1) ss += __shfl_xor(ss, o);
        float s = e / ss;
        if (lane < KC) {
            StT[lane * FST + n] = (_Float16)s;
            g_S[(size_t)(rbase + n) * SP + lane] = s;
            entL += s * logf(s + 1e-15f);
        }
    }
    __syncthreads();

    // xp = S^T h ; G = S^T S (fused, shared A-frag)
    for (int t = wid * 2; t < wid * 2 + 2; ++t) {
        int mt = (t >> 2) << 4, nt = (t & 3) << 4;
        v4f axp = {0.f, 0.f, 0.f, 0.f};
        v4f ag  = {0.f, 0.f, 0.f, 0.f};
        #pragma unroll
        for (int ks = 0; ks < 2; ++ks) {
            v8h af = *(const v8h*)&StT[(mt + l15) * FST + ks * 32 + fko];
            v8h bh = *(const v8h*)&hT[(nt + l15) * FST + ks * 32 + fko];
            v8h bs = *(const v8h*)&StT[(nt + l15) * FST + ks * 32 + fko];
            axp = __builtin_amdgcn_mfma_f32_16x16x32_f16(af, bh, axp, 0, 0, 0);
            ag  = __builtin_amdgcn_mfma_f32_16x16x32_f16(af, bs, ag, 0, 0, 0);
        }
        int col = nt + l15;
        #pragma unroll
        for (int r = 0; r < 4; ++r) {
            int row = mt + quad * 4 + r;
            if (row < KC) {
                g_PTp[(size_t)b * (KC * HD) + row * HD + col] = axp[r];
                if (col < KC)
                    g_Gp[(size_t)b * (KC * KC) + row * KC + col] = ag[r];
            }
        }
    }

    float r = blockReduceN(entL, red, 8);
    if (tid == 0) atomicAdd(&ws[1], r);
}

// ---- K3: AS gather (scalar-loaded global offsets) + wave-row Ap + trace -----
// LDS ~64.7 KB -> 2 blocks/CU. Offset stream on SMEM/SALU, not LDS pipe.
__launch_bounds__(512, 2)
__global__ void k3_as(float* __restrict__ ws)
{
    __shared__ __align__(16) float St[NP * SP];       // 50 KB, packed stride 50
    __shared__ __align__(16) float ASq[64 * SP];      // 12.5 KB (quarter slab)
    __shared__ unsigned int roffL[NP + 1];            // 1 KB
    __shared__ float red[8];

    const int g = blockIdx.x, tid = threadIdx.x;
    const int lane = tid & 63, wid = tid >> 6;
    const int cc = (lane < SP) ? lane : (SP - 1);

    for (int i = tid; i < NP * SP / 4; i += 512)
        ((float4*)St)[i] = ((const float4*)(g_S + (size_t)g * NP * SP))[i];
    if (tid < NP) roffL[tid] = g_roff[g * NP + tid];
    if (tid == NP) roffL[NP] = EPG;
    __syncthreads();

    const unsigned int* gw = g_sdi32 + g * (EPG / 4);   // wave-uniform stream
    const float* Stc = St + cc;

    float ap[7];
    #pragma unroll
    for (int j = 0; j < 7; ++j) ap[j] = 0.f;

    for (int q = 0; q < 4; ++q) {
        // gather 64-row slab: AS[n,c] = sum_{e in row n} S[di_e, c]
        for (int rr = wid * 8; rr < wid * 8 + 8; ++rr) {
            int n = q * 64 + rr;
            int b0 = __builtin_amdgcn_readfirstlane((int)roffL[n]);
            int e1 = __builtin_amdgcn_readfirstlane((int)roffL[n + 1]);
            float a0 = 0.f, a1 = 0.f, a2 = 0.f, a3 = 0.f;
            int e = b0;
            for (; (e & 3) != 0 && e < e1; ++e) {
                unsigned w = gw[e >> 2];
                a0 += Stc[((w >> ((e & 3) * 8)) & 255u) * SP];
            }
            for (; e + 4 <= e1; e += 4) {
                unsigned w = gw[e >> 2];        // s_load: 4 edges per word
                a0 += Stc[(w & 255u) * SP];
                a1 += Stc[((w >> 8) & 255u) * SP];
                a2 += Stc[((w >> 16) & 255u) * SP];
                a3 += Stc[(w >> 24) * SP];
            }
            for (; e < e1; ++e) {
                unsigned w = gw[e >> 2];
                a0 += Stc[((w >> ((e & 3) * 8)) & 255u) * SP];
            }
            if (lane < SP) ASq[rr * SP + lane] = (a0 + a1) + (a2 + a3);
        }
        __syncthreads();

        // Ap[k,c] += sum_n S[n,k]*AS[n,c]; wave w owns k = w + 8j
        for (int n = 0; n < 64; ++n) {
            float as = ASq[n * SP + cc];
            const float* sr = &St[(q * 64 + n) * SP];
            #pragma unroll
            for (int j = 0; j < 7; ++j) {
                int k = wid + j * 8;
                int kcl = (k < SP) ? k : (SP - 1);
                ap[j] += sr[kcl] * as;          // wave-uniform bcast
            }
        }
        __syncthreads();    // before next slab overwrites ASq
    }

    // write Ap; trace accumulates sum(A .* SSt)
    float tr = 0.f;
    #pragma unroll
    for (int j = 0; j < 7; ++j) {
        int k = wid + j * 8;
        if (k < SP && lane < SP) {
            g_Ap[(size_t)g * (KC * KC) + k * KC + lane] = ap[j];
            if (lane == k) tr += ap[j];
        }
    }

    float r = blockReduceN(tr, red, 8);
    if (tid == 0) atomicAdd(&ws[2], r);
}

// ---- K4: combine partials, ||G||^2, dense GIN, classifier -------------------
__launch_bounds__(256, 3)
__global__ void k4_head(const float* __restrict__ W2a, const float* __restrict__ b2a,
                        const float* __restrict__ W2b, const float* __restrict__ b2b,
                        const float* __restrict__ Wl,  const float* __restrict__ bl,
                        float* __restrict__ out, float* __restrict__ ws)
{
    __shared__ __align__(16) float xpL[KC * HD];    // 12.8 KB  xp [k][d]
    __shared__ __align__(16) float Ap[KC * KC];     // 10 KB
    __shared__ __align__(16) float h2[KC * HD];     // 12.8 KB
    __shared__ __align__(16) float tt[KC * HD];     // 12.8 KB
    __shared__ float red[4];

    const int g = blockIdx.x, tid = threadIdx.x;
    const int lane = tid & 63, wid = tid >> 6;

    for (int i = tid; i < KC * HD; i += 256) {
        float v = 0.f;
        #pragma unroll
        for (int c = 0; c < NCH; ++c)
            v += g_PTp[(size_t)(g * NCH + c) * (KC * HD) + i];
        xpL[i] = v;
    }
    float sumG2 = 0.f;
    for (int i = tid; i < KC * KC; i += 256) {
        float v = 0.f;
        #pragma unroll
        for (int c = 0; c < NCH; ++c)
            v += g_Gp[(size_t)(g * NCH + c) * (KC * KC) + i];
        sumG2 += v * v;
        Ap[i] = g_Ap[(size_t)g * (KC * KC) + i];
    }
    __syncthreads();

    // h2[k][d] = xp[k][d] + sum_l Ap[k][l] * xp[l][d]
    for (int k = wid; k < KC; k += 4) {
        float a = xpL[k * HD + lane];
        #pragma unroll
        for (int l = 0; l < KC; ++l)
            a += Ap[k * KC + l] * xpL[l * HD + lane];
        h2[k * HD + lane] = a;
    }
    __syncthreads();

    // t = relu(h2 @ W2a + b2a)
    {
        float wr[HD];
        #pragma unroll
        for (int d = 0; d < HD; ++d) wr[d] = W2a[d * HD + lane];
        float br = b2a[lane];
        for (int k = wid; k < KC; k += 4) {
            float a0 = br, a1 = 0.f, a2 = 0.f, a3 = 0.f;
            const float4* h4 = (const float4*)&h2[k * HD];
            #pragma unroll
            for (int i = 0; i < 16; ++i) {
                float4 v = h4[i];
                a0 += v.x * wr[4*i]; a1 += v.y * wr[4*i+1];
                a2 += v.z * wr[4*i+2]; a3 += v.w * wr[4*i+3];
            }
            tt[k * HD + lane] = fmaxf((a0 + a1) + (a2 + a3), 0.f);
        }
    }
    __syncthreads();

    // h3 = t @ W2b + b2b; fold mean over k and Wl into logits partials
    float l0 = 0.f, l1 = 0.f;
    {
        float wr[HD];
        #pragma unroll
        for (int j = 0; j < HD; ++j) wr[j] = W2b[j * HD + lane];
        float br = b2b[lane];
        float wl0 = Wl[lane * 2], wl1 = Wl[lane * 2 + 1];
        for (int k = wid; k < KC; k += 4) {
            float a0 = br, a1 = 0.f, a2 = 0.f, a3 = 0.f;
            const float4* t4 = (const float4*)&tt[k * HD];
            #pragma unroll
            for (int i = 0; i < 16; ++i) {
                float4 v = t4[i];
                a0 += v.x * wr[4*i]; a1 += v.y * wr[4*i+1];
                a2 += v.z * wr[4*i+2]; a3 += v.w * wr[4*i+3];
            }
            float a = (a0 + a1) + (a2 + a3);
            l0 += a * wl0; l1 += a * wl1;
        }
    }

    float rG2 = blockReduceN(sumG2, red, 4);
    float rl0 = blockReduceN(l0, red, 4);
    float rl1 = blockReduceN(l1, red, 4);
    if (tid == 0) {
        atomicAdd(&ws[3], rG2);
        float g0 = bl[0] + rl0 * (1.f / KC);
        float g1 = bl[1] + rl1 * (1.f / KC);
        float mm = fmaxf(g0, g1);
        float lse = mm + logf(expf(g0 - mm) + expf(g1 - mm));
        out[2 * g]     = g0 - lse;
        out[2 * g + 1] = g1 - lse;
    }
}

extern "C" void kernel_launch(void* const* d_in, const int* in_sizes, int n_in,
                              void* d_out, int out_size, void* d_ws, size_t ws_size,
                              hipStream_t stream) {
    const float* x    = (const float*)d_in[0];
    const float* W1a  = (const float*)d_in[1];
    const float* b1a  = (const float*)d_in[2];
    const float* W1b  = (const float*)d_in[3];
    const float* b1b  = (const float*)d_in[4];
    const float* Wp   = (const float*)d_in[5];
    const float* bp   = (const float*)d_in[6];
    const float* W2a  = (const float*)d_in[7];
    const float* b2a  = (const float*)d_in[8];
    const float* W2b  = (const float*)d_in[9];
    const float* b2b  = (const float*)d_in[10];
    const float* Wl   = (const float*)d_in[11];
    const float* bl   = (const float*)d_in[12];
    const int*   eidx = (const int*)d_in[13];   // [2, E] int32
    float* out = (float*)d_out;
    float* ws  = (float*)d_ws;

    zero_ws<<<1, 64, 0, stream>>>(ws);
    k1a_sort<<<NG, 512, 0, stream>>>(eidx, eidx + ETOT, x);
    k1b_a2<<<NG * 4, 512, 0, stream>>>(eidx, eidx + ETOT, ws);
    k2_mlp<<<NG * NCH, 512, 0, stream>>>(W1a, b1a, W1b, b1b, Wp, bp, ws);
    k3_as<<<NG, 512, 0, stream>>>(ws);
    k4_head<<<NG, 256, 0, stream>>>(W2a, b2a, W2b, b2b, Wl, bl, out, ws);
    finalize_k<<<1, 64, 0, stream>>>(ws, out);
}

// Round 10
// 446.474 us; speedup vs baseline: 1.1739x; 1.0720x over previous
//
#include <hip/hip_runtime.h>
#include <math.h>

// Problem constants (from reference)
#define NG   1024        // graphs
#define NP   256         // nodes per graph
#define EPG  4096        // edges per graph
#define ETOT 4194304     // total edges
#define NTOT (NG * NP)   // 262144 nodes
#define FIN  7
#define HD   64
#define KC   50
#define CHK  64          // rows per K2 chunk
#define NCH  4           // chunks per graph
#define FST  72          // f16 LDS row stride in k2 (144 B rows, 16B-aligned)

// NOTE (R2): __launch_bounds__ 2nd arg acts as CUDA-style min BLOCKS/CU;
// (512,2) => 128-VGPR cap, (512,3) => ~85. Keep per-lane arrays small.
// NOTE (R3): LDS atomic scatter was 1215 us -> counting-sort gather.
// NOTE (R4): persistent per-lane arrays spill at the VGPR cap -> wave-row regs.
// NOTE (R5): GEMV-style phases are latency-bound -> f16 MFMA for k2 GEMMs.
// NOTE (R8): f16 scalar gathers add a cvt per element -> regressed; k3 was
// LDS-pipe bound (2 LDS instr/edge floor).
// NOTE (R10): kill the edge gather entirely: the A^2 count chunk (64x256 u16)
// IS a dense A row-slab. Convert counts->f16 in place, then
// AS = A_slab @ S and Ap_slab = S_slab^T @ AS on MFMA (conventions copied
// from k2's verified tiles). k3_as + si-sort deleted; trace(Ap) moved to k4.

typedef __attribute__((ext_vector_type(8))) _Float16 v8h;
typedef __attribute__((ext_vector_type(4))) float v4f;

// Inter-kernel intermediates as statics: no hipMalloc, graph-capture safe.
// Every element is rewritten each launch before being read.
__device__ float g_xagg[NTOT * 8];                  // x+agg, padded to 8
__device__ _Float16 g_ShT[(size_t)NG * KC * 256];   // S^T per graph [k][n], f16
__device__ float g_PTp[(size_t)NG * NCH * KC * HD]; // xp partials [k][d]
__device__ float g_Gp[(size_t)NG * NCH * KC * KC];  // G partials [k][c]
__device__ float g_Ap4[(size_t)NG * 4 * KC * KC];   // Ap slab-partials [k][c]

__global__ void zero_ws(float* ws) {
    if (threadIdx.x < 4) ws[threadIdx.x] = 0.f;
}

// ws[0]=sumA2, ws[1]=sum S logS, ws[2]=trace(Ap)=sum(A.SSt), ws[3]=||G||^2
__global__ void finalize_k(const float* __restrict__ ws, float* __restrict__ out) {
    if (threadIdx.x == 0) {
        float num = ws[0] - 2.f * ws[2] + ws[3];
        float link = sqrtf(fmaxf(num, 0.f)) / 67108864.0f;   // / (B*n*n)
        float ent  = -ws[1] / 262144.0f;                     // / N
        out[2048] = link + ent;
    }
}

__device__ __forceinline__ float blockReduceN(float v, float* red, int nw) {
    __syncthreads();
    #pragma unroll
    for (int o = 32; o > 0; o >>= 1) v += __shfl_down(v, o);
    if ((threadIdx.x & 63) == 0) red[threadIdx.x >> 6] = v;
    __syncthreads();
    float r = 0.f;
    if (threadIdx.x == 0) {
        for (int i = 0; i < nw; ++i) r += red[i];
    }
    return r;
}

// ---- K1a: di counting sort + gather GIN aggregation -------------------------
// LDS ~25 KB -> 3 blocks/CU
__launch_bounds__(512, 3)
__global__ void k1a_sort(const int* __restrict__ esrc, const int* __restrict__ edst,
                         const float* __restrict__ x)
{
    __shared__ unsigned short cells[EPG];       // 8 KB
    __shared__ unsigned char ssi[EPG];          // 4 KB  (di-sorted si)
    __shared__ float xt8[NP * 8];               // 8 KB  (x, stride 8, pad 0)
    __shared__ unsigned int hist_di[256], cur_di[256];
    __shared__ unsigned int roff_di[NP + 1];

    const int g = blockIdx.x, tid = threadIdx.x;
    const int lane = tid & 63, wid = tid >> 6;

    if (tid < 256) hist_di[tid] = 0u;
    __syncthreads();

    for (int e = tid; e < EPG; e += 512) {
        int s = esrc[g * EPG + e] & (NP - 1);
        int d = edst[g * EPG + e] & (NP - 1);
        cells[e] = (unsigned short)((s << 8) | d);
        atomicAdd(&hist_di[d], 1u);
    }
    for (int i = tid; i < NP * 8; i += 512) {
        int n = i >> 3, f = i & 7;
        xt8[i] = (f < FIN) ? x[g * NP * FIN + n * FIN + f] : 0.f;
    }
    __syncthreads();

    // exclusive scan (wave 0)
    if (wid == 0) {
        unsigned carry = 0;
        for (int c = 0; c < 4; ++c) {
            unsigned v = hist_di[c * 64 + lane];
            unsigned s = v;
            #pragma unroll
            for (int o = 1; o < 64; o <<= 1) {
                unsigned t = __shfl_up(s, o);
                if (lane >= o) s += t;
            }
            unsigned excl = s - v + carry;
            roff_di[c * 64 + lane] = excl;
            cur_di[c * 64 + lane] = excl;
            carry += __shfl(s, 63);
        }
        if (lane == 0) roff_di[NP] = EPG;
    }
    __syncthreads();

    for (int e = tid; e < EPG; e += 512) {
        int c = cells[e]; int si = c >> 8, di = c & 255;
        unsigned p2 = atomicAdd(&cur_di[di], 1u);
        ssi[p2] = (unsigned char)si;
    }
    __syncthreads();

    // gather agg: 8 lanes per node (f = lane&7), write x+agg
    {
        const int gidx = tid >> 3, f = tid & 7;
        for (int n = gidx; n < NP; n += 64) {
            int beg = roff_di[n], end = roff_di[n + 1];
            float a = xt8[n * 8 + f];
            for (int e = beg; e < end; ++e)
                a += xt8[ssi[e] * 8 + f];
            g_xagg[g * NP * 8 + n * 8 + f] = a;
        }
    }
}

// ---- K2: MFMA f16 — MLP1, h-GEMM, P-GEMM, softmax, xp/G-GEMMs ---------------
__launch_bounds__(512, 2)
__global__ void k2_mlp(const float* __restrict__ W1a, const float* __restrict__ b1a,
                       const float* __restrict__ W1b, const float* __restrict__ b1b,
                       const float* __restrict__ Wp,  const float* __restrict__ bp,
                       float* __restrict__ ws)
{
    __shared__ __align__(16) float xt[CHK * 8];          // 2 KB
    __shared__ __align__(16) _Float16 t1b[CHK * FST];    // 9.2 KB  t1   [n][j]
    __shared__ __align__(16) _Float16 W1bT[HD * FST];    // 9.2 KB  W1b^T[d][j]
    __shared__ __align__(16) _Float16 WpT[HD * FST];     // 9.2 KB  Wp^T [k][d]
    __shared__ __align__(16) _Float16 hN[CHK * FST];     // 9.2 KB  h    [n][d]
    __shared__ __align__(16) _Float16 hT[HD * FST];      // 9.2 KB  h^T  [d][n]
    __shared__ __align__(16) _Float16 StT[HD * FST];     // 9.2 KB  S^T  [k][n]
    __shared__ __align__(16) float Pf[CHK * 66];         // 16.9 KB P    [n][k]
    __shared__ float red[8];

    const int b = blockIdx.x, rbase = b * CHK, tid = threadIdx.x;
    const int g = b >> 2, ch = b & 3;
    const int lane = tid & 63, wid = tid >> 6;
    const int l15 = lane & 15, quad = lane >> 4;
    const int fko = quad * 8;

    xt[tid] = g_xagg[rbase * 8 + tid];
    for (int i = tid; i < HD * HD; i += 512) {
        int j = i >> 6, d = i & 63;
        W1bT[d * FST + j] = (_Float16)W1b[i];
    }
    for (int i = tid; i < HD * KC; i += 512) {
        int d = i / KC, k = i - d * KC;
        WpT[k * FST + d] = (_Float16)Wp[i];
    }
    __syncthreads();

    // t1 = relu((x+agg) @ W1a + b1a)
    {
        float w1r[FIN];
        #pragma unroll
        for (int f = 0; f < FIN; ++f) w1r[f] = W1a[f * HD + lane];
        float br = b1a[lane];
        for (int n = wid; n < CHK; n += 8) {
            float a = br;
            #pragma unroll
            for (int f = 0; f < FIN; ++f) a += xt[n * 8 + f] * w1r[f];
            t1b[n * FST + lane] = (_Float16)fmaxf(a, 0.f);
        }
    }
    __syncthreads();

    // h = t1 @ W1b + b1b
    for (int t = wid * 2; t < wid * 2 + 2; ++t) {
        int mt = (t >> 2) << 4, nt = (t & 3) << 4;
        v4f acc = {0.f, 0.f, 0.f, 0.f};
        #pragma unroll
        for (int ks = 0; ks < 2; ++ks) {
            v8h af = *(const v8h*)&t1b[(mt + l15) * FST + ks * 32 + fko];
            v8h bf = *(const v8h*)&W1bT[(nt + l15) * FST + ks * 32 + fko];
            acc = __builtin_amdgcn_mfma_f32_16x16x32_f16(af, bf, acc, 0, 0, 0);
        }
        int d = nt + l15;
        float bv = b1b[d];
        #pragma unroll
        for (int r = 0; r < 4; ++r) {
            int m = mt + quad * 4 + r;
            _Float16 hv = (_Float16)(acc[r] + bv);
            hN[m * FST + d] = hv;
            hT[d * FST + m] = hv;
        }
    }
    __syncthreads();

    // P = h @ Wp + bp
    for (int t = wid * 2; t < wid * 2 + 2; ++t) {
        int mt = (t >> 2) << 4, nt = (t & 3) << 4;
        v4f acc = {0.f, 0.f, 0.f, 0.f};
        #pragma unroll
        for (int ks = 0; ks < 2; ++ks) {
            v8h af = *(const v8h*)&hN[(mt + l15) * FST + ks * 32 + fko];
            v8h bf = *(const v8h*)&WpT[(nt + l15) * FST + ks * 32 + fko];
            acc = __builtin_amdgcn_mfma_f32_16x16x32_f16(af, bf, acc, 0, 0, 0);
        }
        int kcol = nt + l15;
        if (kcol < KC) {
            float bv = bp[kcol];
            #pragma unroll
            for (int r = 0; r < 4; ++r)
                Pf[(mt + quad * 4 + r) * 66 + kcol] = acc[r] + bv;
        }
    }
    __syncthreads();

    // softmax -> StT f16 [k][n], entropy partial
    float entL = 0.f;
    for (int n = wid; n < CHK; n += 8) {
        float a = (lane < KC) ? Pf[n * 66 + lane] : -INFINITY;
        float m = a;
        #pragma unroll
        for (int o = 32; o > 0; o >>= 1) m = fmaxf(m, __shfl_xor(m, o));
        float e = expf(a - m);
        float ss = e;
        #pragma unroll
        for (int o = 32; o > 0; o >>= 1) ss += __shfl_xor(ss, o);
        float s = e / ss;
        if (lane < KC) {
            StT[lane * FST + n] = (_Float16)s;
            entL += s * logf(s + 1e-15f);
        }
    }
    __syncthreads();

    // persist S^T chunk to g_ShT (coalesced u32 rows)
    for (int i = tid; i < KC * 32; i += 512) {
        int k = i >> 5, o = i & 31;     // o: u32 index within 64-col chunk
        unsigned w = *(const unsigned int*)&StT[k * FST + 2 * o];
        ((unsigned int*)g_ShT)[((size_t)g * KC + k) * 128 + ch * 32 + o] = w;
    }

    // xp = S^T h ; G = S^T S (fused, shared A-frag)
    for (int t = wid * 2; t < wid * 2 + 2; ++t) {
        int mt = (t >> 2) << 4, nt = (t & 3) << 4;
        v4f axp = {0.f, 0.f, 0.f, 0.f};
        v4f ag  = {0.f, 0.f, 0.f, 0.f};
        #pragma unroll
        for (int ks = 0; ks < 2; ++ks) {
            v8h af = *(const v8h*)&StT[(mt + l15) * FST + ks * 32 + fko];
            v8h bh = *(const v8h*)&hT[(nt + l15) * FST + ks * 32 + fko];
            v8h bs = *(const v8h*)&StT[(nt + l15) * FST + ks * 32 + fko];
            axp = __builtin_amdgcn_mfma_f32_16x16x32_f16(af, bh, axp, 0, 0, 0);
            ag  = __builtin_amdgcn_mfma_f32_16x16x32_f16(af, bs, ag, 0, 0, 0);
        }
        int col = nt + l15;
        #pragma unroll
        for (int r = 0; r < 4; ++r) {
            int row = mt + quad * 4 + r;
            if (row < KC) {
                g_PTp[(size_t)b * (KC * HD) + row * HD + col] = axp[r];
                if (col < KC)
                    g_Gp[(size_t)b * (KC * KC) + row * KC + col] = ag[r];
            }
        }
    }

    float r = blockReduceN(entL, red, 8);
    if (tid == 0) atomicAdd(&ws[1], r);
}

// ---- K3_fused: dense-A slab count + sum(A^2) + MFMA AS & Ap slab-partial ----
// blockIdx = g*4 + slab (64 A-rows each). LDS ~73 KB -> 2 blocks/CU.
__launch_bounds__(512, 2)
__global__ void k3_fused(const int* __restrict__ esrc, const int* __restrict__ edst,
                         float* __restrict__ ws)
{
    __shared__ unsigned int cnt[8192];               // 32 KB; becomes f16 A[64][256]
    __shared__ __align__(16) _Float16 ST[64 * 256];  // 32 KB  S^T [k][n], rows>=50 = 0
    __shared__ __align__(16) _Float16 T1T[64 * 72];  // 9 KB   AS^T [c][nrow]
    __shared__ float red[8];

    const int g = blockIdx.x >> 2, ch = blockIdx.x & 3, tid = threadIdx.x;
    const int lane = tid & 63, wid = tid >> 6;
    const int l15 = lane & 15, quad = lane >> 4, fko = quad * 8;

    for (int i = tid; i < 8192; i += 512) cnt[i] = 0u;
    // stage S^T (zero pad rows k >= 50)
    for (int i = tid; i < 64 * 128; i += 512) {
        int k = i >> 7, o = i & 127;
        ((unsigned int*)ST)[i] = (k < KC)
            ? ((const unsigned int*)g_ShT)[((size_t)g * KC + k) * 128 + o] : 0u;
    }
    __syncthreads();

    // count this slab's cells (rows s in [ch*64, ch*64+64))
    int base = ch << 14;
    for (int e = tid; e < EPG; e += 512) {
        int s = esrc[g * EPG + e] & (NP - 1);
        int d = edst[g * EPG + e] & (NP - 1);
        int r = ((s << 8) | d) - base;
        if ((unsigned)r < 16384u)
            atomicAdd(&cnt[r >> 1], (r & 1) ? 0x10000u : 1u);
    }
    __syncthreads();

    // sum(A^2) partial + in-place convert counts -> f16 (each word one owner)
    float sumA2 = 0.f;
    for (int i = tid; i < 8192; i += 512) {
        unsigned v = cnt[i];
        float m0 = (float)(v & 0xffffu), m1 = (float)(v >> 16);
        sumA2 += m0 * m0 + m1 * m1;
        union { unsigned u; _Float16 h[2]; } cv;
        cv.h[0] = (_Float16)m0; cv.h[1] = (_Float16)m1;
        cnt[i] = cv.u;
    }
    __syncthreads();

    const _Float16* Af = (const _Float16*)cnt;   // A slab [64][256] row-major

    // AS_slab = A_slab @ S : M=64 (nrow), N=64 (c, >=50 zero), K=256
    for (int t = wid * 2; t < wid * 2 + 2; ++t) {
        int mt = (t >> 2) << 4, nt = (t & 3) << 4;
        v4f acc = {0.f, 0.f, 0.f, 0.f};
        #pragma unroll
        for (int ks = 0; ks < 8; ++ks) {
            v8h af = *(const v8h*)&Af[(mt + l15) * 256 + ks * 32 + fko];
            v8h bf = *(const v8h*)&ST[(nt + l15) * 256 + ks * 32 + fko];
            acc = __builtin_amdgcn_mfma_f32_16x16x32_f16(af, bf, acc, 0, 0, 0);
        }
        int c = nt + l15;
        #pragma unroll
        for (int r = 0; r < 4; ++r)
            T1T[c * 72 + mt + quad * 4 + r] = (_Float16)acc[r];
    }
    __syncthreads();

    // Ap_slab[k][c] = sum_{n in slab} S[n][k] * AS[n][c] : M=k, N=c, K=64
    for (int t = wid * 2; t < wid * 2 + 2; ++t) {
        int mt = (t >> 2) << 4, nt = (t & 3) << 4;
        v4f acc = {0.f, 0.f, 0.f, 0.f};
        #pragma unroll
        for (int ks = 0; ks < 2; ++ks) {
            v8h af = *(const v8h*)&ST[(mt + l15) * 256 + ch * 64 + ks * 32 + fko];
            v8h bf = *(const v8h*)&T1T[(nt + l15) * 72 + ks * 32 + fko];
            acc = __builtin_amdgcn_mfma_f32_16x16x32_f16(af, bf, acc, 0, 0, 0);
        }
        int c = nt + l15;
        if (c < KC) {
            #pragma unroll
            for (int r = 0; r < 4; ++r) {
                int k = mt + quad * 4 + r;
                if (k < KC)
                    g_Ap4[(size_t)blockIdx.x * (KC * KC) + k * KC + c] = acc[r];
            }
        }
    }

    float r = blockReduceN(sumA2, red, 8);
    if (tid == 0) atomicAdd(&ws[0], r);
}

// ---- K4: combine partials, ||G||^2, trace(Ap), dense GIN, classifier --------
__launch_bounds__(256, 3)
__global__ void k4_head(const float* __restrict__ W2a, const float* __restrict__ b2a,
                        const float* __restrict__ W2b, const float* __restrict__ b2b,
                        const float* __restrict__ Wl,  const float* __restrict__ bl,
                        float* __restrict__ out, float* __restrict__ ws)
{
    __shared__ __align__(16) float xpL[KC * HD];    // 12.8 KB  xp [k][d]
    __shared__ __align__(16) float Ap[KC * KC];     // 10 KB
    __shared__ __align__(16) float h2[KC * HD];     // 12.8 KB
    __shared__ __align__(16) float tt[KC * HD];     // 12.8 KB
    __shared__ float red[4];

    const int g = blockIdx.x, tid = threadIdx.x;
    const int lane = tid & 63, wid = tid >> 6;

    for (int i = tid; i < KC * HD; i += 256) {
        float v = 0.f;
        #pragma unroll
        for (int c = 0; c < NCH; ++c)
            v += g_PTp[(size_t)(g * NCH + c) * (KC * HD) + i];
        xpL[i] = v;
    }
    float sumG2 = 0.f, trL = 0.f;
    for (int i = tid; i < KC * KC; i += 256) {
        float v = 0.f, a = 0.f;
        #pragma unroll
        for (int c = 0; c < NCH; ++c) {
            v += g_Gp[(size_t)(g * NCH + c) * (KC * KC) + i];
            a += g_Ap4[(size_t)(g * 4 + c) * (KC * KC) + i];
        }
        sumG2 += v * v;
        Ap[i] = a;
        if (i % (KC + 1) == 0) trL += a;     // diagonal: i = k*(KC+1)
    }
    __syncthreads();

    // h2[k][d] = xp[k][d] + sum_l Ap[k][l] * xp[l][d]
    for (int k = wid; k < KC; k += 4) {
        float a = xpL[k * HD + lane];
        #pragma unroll
        for (int l = 0; l < KC; ++l)
            a += Ap[k * KC + l] * xpL[l * HD + lane];
        h2[k * HD + lane] = a;
    }
    __syncthreads();

    // t = relu(h2 @ W2a + b2a)
    {
        float wr[HD];
        #pragma unroll
        for (int d = 0; d < HD; ++d) wr[d] = W2a[d * HD + lane];
        float br = b2a[lane];
        for (int k = wid; k < KC; k += 4) {
            float a0 = br, a1 = 0.f, a2 = 0.f, a3 = 0.f;
            const float4* h4 = (const float4*)&h2[k * HD];
            #pragma unroll
            for (int i = 0; i < 16; ++i) {
                float4 v = h4[i];
                a0 += v.x * wr[4*i]; a1 += v.y * wr[4*i+1];
                a2 += v.z * wr[4*i+2]; a3 += v.w * wr[4*i+3];
            }
            tt[k * HD + lane] = fmaxf((a0 + a1) + (a2 + a3), 0.f);
        }
    }
    __syncthreads();

    // h3 = t @ W2b + b2b; fold mean over k and Wl into logits partials
    float l0 = 0.f, l1 = 0.f;
    {
        float wr[HD];
        #pragma unroll
        for (int j = 0; j < HD; ++j) wr[j] = W2b[j * HD + lane];
        float br = b2b[lane];
        float wl0 = Wl[lane * 2], wl1 = Wl[lane * 2 + 1];
        for (int k = wid; k < KC; k += 4) {
            float a0 = br, a1 = 0.f, a2 = 0.f, a3 = 0.f;
            const float4* t4 = (const float4*)&tt[k * HD];
            #pragma unroll
            for (int i = 0; i < 16; ++i) {
                float4 v = t4[i];
                a0 += v.x * wr[4*i]; a1 += v.y * wr[4*i+1];
                a2 += v.z * wr[4*i+2]; a3 += v.w * wr[4*i+3];
            }
            float a = (a0 + a1) + (a2 + a3);
            l0 += a * wl0; l1 += a * wl1;
        }
    }

    float rG2 = blockReduceN(sumG2, red, 4);
    float rTr = blockReduceN(trL, red, 4);
    float rl0 = blockReduceN(l0, red, 4);
    float rl1 = blockReduceN(l1, red, 4);
    if (tid == 0) {
        atomicAdd(&ws[3], rG2);
        atomicAdd(&ws[2], rTr);
        float g0 = bl[0] + rl0 * (1.f / KC);
        float g1 = bl[1] + rl1 * (1.f / KC);
        float mm = fmaxf(g0, g1);
        float lse = mm + logf(expf(g0 - mm) + expf(g1 - mm));
        out[2 * g]     = g0 - lse;
        out[2 * g + 1] = g1 - lse;
    }
}

extern "C" void kernel_launch(void* const* d_in, const int* in_sizes, int n_in,
                              void* d_out, int out_size, void* d_ws, size_t ws_size,
                              hipStream_t stream) {
    const float* x    = (const float*)d_in[0];
    const float* W1a  = (const float*)d_in[1];
    const float* b1a  = (const float*)d_in[2];
    const float* W1b  = (const float*)d_in[3];
    const float* b1b  = (const float*)d_in[4];
    const float* Wp   = (const float*)d_in[5];
    const float* bp   = (const float*)d_in[6];
    const float* W2a  = (const float*)d_in[7];
    const float* b2a  = (const float*)d_in[8];
    const float* W2b  = (const float*)d_in[9];
    const float* b2b  = (const float*)d_in[10];
    const float* Wl   = (const float*)d_in[11];
    const float* bl   = (const float*)d_in[12];
    const int*   eidx = (const int*)d_in[13];   // [2, E] int32
    float* out = (float*)d_out;
    float* ws  = (float*)d_ws;

    zero_ws<<<1, 64, 0, stream>>>(ws);
    k1a_sort<<<NG, 512, 0, stream>>>(eidx, eidx + ETOT, x);
    k2_mlp<<<NG * NCH, 512, 0, stream>>>(W1a, b1a, W1b, b1b, Wp, bp, ws);
    k3_fused<<<NG * 4, 512, 0, stream>>>(eidx, eidx + ETOT, ws);
    k4_head<<<NG, 256, 0, stream>>>(W2a, b2a, W2b, b2b, Wl, bl, out, ws);
    finalize_k<<<1, 64, 0, stream>>>(ws, out);
}

// Round 11
// 414.433 us; speedup vs baseline: 1.2646x; 1.0773x over previous
//
#include <hip/hip_runtime.h>
#include <math.h>

// Problem constants (from reference)
#define NG   1024        // graphs
#define NP   256         // nodes per graph
#define EPG  4096        // edges per graph
#define ETOT 4194304     // total edges
#define NTOT (NG * NP)   // 262144 nodes
#define FIN  7
#define HD   64
#define KC   50
#define CHK  64          // rows per K2 chunk
#define NCH  4           // chunks per graph
#define FST  72          // f16 LDS row stride in k2 (144 B rows, 16B-aligned)
#define ASTR 264         // k3 A/ST f16 row stride: 132 words = 4 mod 32 (2-way free)
#define ASTW 132         // ASTR in u32 words

// NOTE (R2): __launch_bounds__ 2nd arg acts as CUDA-style min BLOCKS/CU;
// (512,2) => 128-VGPR cap, (512,3) => ~85. Keep per-lane arrays small.
// NOTE (R3): LDS atomic scatter was 1215 us -> counting-sort gather.
// NOTE (R4): persistent per-lane arrays spill at the VGPR cap -> wave-row regs.
// NOTE (R5): GEMV-style phases are latency-bound -> f16 MFMA for k2 GEMMs.
// NOTE (R8): f16 scalar gathers add a cvt per element -> regressed.
// NOTE (R10): densify A per 64-row slab inside the count kernel; AS and Ap on
// MFMA. Worked (142 us of gather gone) BUT raw 256-f16 row stride = 128 words
// = 0 mod 32 -> every frag read 16-way bank conflict (3.4e7 cycles).
// NOTE (R11): pad A/ST rows to 264 f16 (132 words = 4 mod 32, free 2-way).

typedef __attribute__((ext_vector_type(8))) _Float16 v8h;
typedef __attribute__((ext_vector_type(4))) float v4f;

// Inter-kernel intermediates as statics: no hipMalloc, graph-capture safe.
// Every element is rewritten each launch before being read.
__device__ float g_xagg[NTOT * 8];                  // x+agg, padded to 8
__device__ _Float16 g_ShT[(size_t)NG * KC * 256];   // S^T per graph [k][n], f16
__device__ float g_PTp[(size_t)NG * NCH * KC * HD]; // xp partials [k][d]
__device__ float g_Gp[(size_t)NG * NCH * KC * KC];  // G partials [k][c]
__device__ float g_Ap4[(size_t)NG * 4 * KC * KC];   // Ap slab-partials [k][c]

__global__ void zero_ws(float* ws) {
    if (threadIdx.x < 4) ws[threadIdx.x] = 0.f;
}

// ws[0]=sumA2, ws[1]=sum S logS, ws[2]=trace(Ap)=sum(A.SSt), ws[3]=||G||^2
__global__ void finalize_k(const float* __restrict__ ws, float* __restrict__ out) {
    if (threadIdx.x == 0) {
        float num = ws[0] - 2.f * ws[2] + ws[3];
        float link = sqrtf(fmaxf(num, 0.f)) / 67108864.0f;   // / (B*n*n)
        float ent  = -ws[1] / 262144.0f;                     // / N
        out[2048] = link + ent;
    }
}

__device__ __forceinline__ float blockReduceN(float v, float* red, int nw) {
    __syncthreads();
    #pragma unroll
    for (int o = 32; o > 0; o >>= 1) v += __shfl_down(v, o);
    if ((threadIdx.x & 63) == 0) red[threadIdx.x >> 6] = v;
    __syncthreads();
    float r = 0.f;
    if (threadIdx.x == 0) {
        for (int i = 0; i < nw; ++i) r += red[i];
    }
    return r;
}

// ---- K1a: di counting sort + gather GIN aggregation -------------------------
// LDS ~25 KB -> 3 blocks/CU
__launch_bounds__(512, 3)
__global__ void k1a_sort(const int* __restrict__ esrc, const int* __restrict__ edst,
                         const float* __restrict__ x)
{
    __shared__ unsigned short cells[EPG];       // 8 KB
    __shared__ unsigned char ssi[EPG];          // 4 KB  (di-sorted si)
    __shared__ float xt8[NP * 8];               // 8 KB  (x, stride 8, pad 0)
    __shared__ unsigned int hist_di[256], cur_di[256];
    __shared__ unsigned int roff_di[NP + 1];

    const int g = blockIdx.x, tid = threadIdx.x;
    const int lane = tid & 63, wid = tid >> 6;

    if (tid < 256) hist_di[tid] = 0u;
    __syncthreads();

    for (int e = tid; e < EPG; e += 512) {
        int s = esrc[g * EPG + e] & (NP - 1);
        int d = edst[g * EPG + e] & (NP - 1);
        cells[e] = (unsigned short)((s << 8) | d);
        atomicAdd(&hist_di[d], 1u);
    }
    for (int i = tid; i < NP * 8; i += 512) {
        int n = i >> 3, f = i & 7;
        xt8[i] = (f < FIN) ? x[g * NP * FIN + n * FIN + f] : 0.f;
    }
    __syncthreads();

    // exclusive scan (wave 0)
    if (wid == 0) {
        unsigned carry = 0;
        for (int c = 0; c < 4; ++c) {
            unsigned v = hist_di[c * 64 + lane];
            unsigned s = v;
            #pragma unroll
            for (int o = 1; o < 64; o <<= 1) {
                unsigned t = __shfl_up(s, o);
                if (lane >= o) s += t;
            }
            unsigned excl = s - v + carry;
            roff_di[c * 64 + lane] = excl;
            cur_di[c * 64 + lane] = excl;
            carry += __shfl(s, 63);
        }
        if (lane == 0) roff_di[NP] = EPG;
    }
    __syncthreads();

    for (int e = tid; e < EPG; e += 512) {
        int c = cells[e]; int si = c >> 8, di = c & 255;
        unsigned p2 = atomicAdd(&cur_di[di], 1u);
        ssi[p2] = (unsigned char)si;
    }
    __syncthreads();

    // gather agg: 8 lanes per node (f = lane&7), write x+agg
    {
        const int gidx = tid >> 3, f = tid & 7;
        for (int n = gidx; n < NP; n += 64) {
            int beg = roff_di[n], end = roff_di[n + 1];
            float a = xt8[n * 8 + f];
            for (int e = beg; e < end; ++e)
                a += xt8[ssi[e] * 8 + f];
            g_xagg[g * NP * 8 + n * 8 + f] = a;
        }
    }
}

// ---- K2: MFMA f16 — MLP1, h-GEMM, P-GEMM, softmax, xp/G-GEMMs ---------------
__launch_bounds__(512, 2)
__global__ void k2_mlp(const float* __restrict__ W1a, const float* __restrict__ b1a,
                       const float* __restrict__ W1b, const float* __restrict__ b1b,
                       const float* __restrict__ Wp,  const float* __restrict__ bp,
                       float* __restrict__ ws)
{
    __shared__ __align__(16) float xt[CHK * 8];          // 2 KB
    __shared__ __align__(16) _Float16 t1b[CHK * FST];    // 9.2 KB  t1   [n][j]
    __shared__ __align__(16) _Float16 W1bT[HD * FST];    // 9.2 KB  W1b^T[d][j]
    __shared__ __align__(16) _Float16 WpT[HD * FST];     // 9.2 KB  Wp^T [k][d]
    __shared__ __align__(16) _Float16 hN[CHK * FST];     // 9.2 KB  h    [n][d]
    __shared__ __align__(16) _Float16 hT[HD * FST];      // 9.2 KB  h^T  [d][n]
    __shared__ __align__(16) _Float16 StT[HD * FST];     // 9.2 KB  S^T  [k][n]
    __shared__ __align__(16) float Pf[CHK * 66];         // 16.9 KB P    [n][k]
    __shared__ float red[8];

    const int b = blockIdx.x, rbase = b * CHK, tid = threadIdx.x;
    const int g = b >> 2, ch = b & 3;
    const int lane = tid & 63, wid = tid >> 6;
    const int l15 = lane & 15, quad = lane >> 4;
    const int fko = quad * 8;

    xt[tid] = g_xagg[rbase * 8 + tid];
    for (int i = tid; i < HD * HD; i += 512) {
        int j = i >> 6, d = i & 63;
        W1bT[d * FST + j] = (_Float16)W1b[i];
    }
    for (int i = tid; i < HD * KC; i += 512) {
        int d = i / KC, k = i - d * KC;
        WpT[k * FST + d] = (_Float16)Wp[i];
    }
    __syncthreads();

    // t1 = relu((x+agg) @ W1a + b1a)
    {
        float w1r[FIN];
        #pragma unroll
        for (int f = 0; f < FIN; ++f) w1r[f] = W1a[f * HD + lane];
        float br = b1a[lane];
        for (int n = wid; n < CHK; n += 8) {
            float a = br;
            #pragma unroll
            for (int f = 0; f < FIN; ++f) a += xt[n * 8 + f] * w1r[f];
            t1b[n * FST + lane] = (_Float16)fmaxf(a, 0.f);
        }
    }
    __syncthreads();

    // h = t1 @ W1b + b1b
    for (int t = wid * 2; t < wid * 2 + 2; ++t) {
        int mt = (t >> 2) << 4, nt = (t & 3) << 4;
        v4f acc = {0.f, 0.f, 0.f, 0.f};
        #pragma unroll
        for (int ks = 0; ks < 2; ++ks) {
            v8h af = *(const v8h*)&t1b[(mt + l15) * FST + ks * 32 + fko];
            v8h bf = *(const v8h*)&W1bT[(nt + l15) * FST + ks * 32 + fko];
            acc = __builtin_amdgcn_mfma_f32_16x16x32_f16(af, bf, acc, 0, 0, 0);
        }
        int d = nt + l15;
        float bv = b1b[d];
        #pragma unroll
        for (int r = 0; r < 4; ++r) {
            int m = mt + quad * 4 + r;
            _Float16 hv = (_Float16)(acc[r] + bv);
            hN[m * FST + d] = hv;
            hT[d * FST + m] = hv;
        }
    }
    __syncthreads();

    // P = h @ Wp + bp
    for (int t = wid * 2; t < wid * 2 + 2; ++t) {
        int mt = (t >> 2) << 4, nt = (t & 3) << 4;
        v4f acc = {0.f, 0.f, 0.f, 0.f};
        #pragma unroll
        for (int ks = 0; ks < 2; ++ks) {
            v8h af = *(const v8h*)&hN[(mt + l15) * FST + ks * 32 + fko];
            v8h bf = *(const v8h*)&WpT[(nt + l15) * FST + ks * 32 + fko];
            acc = __builtin_amdgcn_mfma_f32_16x16x32_f16(af, bf, acc, 0, 0, 0);
        }
        int kcol = nt + l15;
        if (kcol < KC) {
            float bv = bp[kcol];
            #pragma unroll
            for (int r = 0; r < 4; ++r)
                Pf[(mt + quad * 4 + r) * 66 + kcol] = acc[r] + bv;
        }
    }
    __syncthreads();

    // softmax -> StT f16 [k][n], entropy partial
    float entL = 0.f;
    for (int n = wid; n < CHK; n += 8) {
        float a = (lane < KC) ? Pf[n * 66 + lane] : -INFINITY;
        float m = a;
        #pragma unroll
        for (int o = 32; o > 0; o >>= 1) m = fmaxf(m, __shfl_xor(m, o));
        float e = expf(a - m);
        float ss = e;
        #pragma unroll
        for (int o = 32; o > 0; o >>= 1) ss += __shfl_xor(ss, o);
        float s = e / ss;
        if (lane < KC) {
            StT[lane * FST + n] = (_Float16)s;
            entL += s * logf(s + 1e-15f);
        }
    }
    __syncthreads();

    // persist S^T chunk to g_ShT (coalesced u32 rows)
    for (int i = tid; i < KC * 32; i += 512) {
        int k = i >> 5, o = i & 31;     // o: u32 index within 64-col chunk
        unsigned w = *(const unsigned int*)&StT[k * FST + 2 * o];
        ((unsigned int*)g_ShT)[((size_t)g * KC + k) * 128 + ch * 32 + o] = w;
    }

    // xp = S^T h ; G = S^T S (fused, shared A-frag)
    for (int t = wid * 2; t < wid * 2 + 2; ++t) {
        int mt = (t >> 2) << 4, nt = (t & 3) << 4;
        v4f axp = {0.f, 0.f, 0.f, 0.f};
        v4f ag  = {0.f, 0.f, 0.f, 0.f};
        #pragma unroll
        for (int ks = 0; ks < 2; ++ks) {
            v8h af = *(const v8h*)&StT[(mt + l15) * FST + ks * 32 + fko];
            v8h bh = *(const v8h*)&hT[(nt + l15) * FST + ks * 32 + fko];
            v8h bs = *(const v8h*)&StT[(nt + l15) * FST + ks * 32 + fko];
            axp = __builtin_amdgcn_mfma_f32_16x16x32_f16(af, bh, axp, 0, 0, 0);
            ag  = __builtin_amdgcn_mfma_f32_16x16x32_f16(af, bs, ag, 0, 0, 0);
        }
        int col = nt + l15;
        #pragma unroll
        for (int r = 0; r < 4; ++r) {
            int row = mt + quad * 4 + r;
            if (row < KC) {
                g_PTp[(size_t)b * (KC * HD) + row * HD + col] = axp[r];
                if (col < KC)
                    g_Gp[(size_t)b * (KC * KC) + row * KC + col] = ag[r];
            }
        }
    }

    float r = blockReduceN(entL, red, 8);
    if (tid == 0) atomicAdd(&ws[1], r);
}

// ---- K3_fused: dense-A slab count + sum(A^2) + MFMA AS & Ap slab-partial ----
// blockIdx = g*4 + slab (64 A-rows each). Rows padded to 264 f16 (stride
// 132 words = 4 mod 32 -> free 2-way on frag reads). LDS ~77 KB -> 2 blocks/CU.
__launch_bounds__(512, 2)
__global__ void k3_fused(const int* __restrict__ esrc, const int* __restrict__ edst,
                         float* __restrict__ ws)
{
    __shared__ unsigned int cnt[64 * ASTW];          // 33 KB; becomes f16 A[64][264]
    __shared__ __align__(16) _Float16 ST[64 * ASTR]; // 33 KB  S^T [k][n] padded
    __shared__ __align__(16) _Float16 T1T[64 * 72];  // 9 KB   AS^T [c][nrow]
    __shared__ float red[8];

    const int g = blockIdx.x >> 2, ch = blockIdx.x & 3, tid = threadIdx.x;
    const int lane = tid & 63, wid = tid >> 6;
    const int l15 = lane & 15, quad = lane >> 4, fko = quad * 8;

    for (int i = tid; i < 64 * ASTW; i += 512) cnt[i] = 0u;
    // stage S^T into padded rows (zero rows k >= 50; zero col pads)
    for (int i = tid; i < 64 * 128; i += 512) {
        int k = i >> 7, o = i & 127;
        ((unsigned int*)ST)[k * ASTW + o] = (k < KC)
            ? ((const unsigned int*)g_ShT)[((size_t)g * KC + k) * 128 + o] : 0u;
    }
    for (int i = tid; i < 64 * 4; i += 512)          // col pads (words 128..131)
        ((unsigned int*)ST)[(i >> 2) * ASTW + 128 + (i & 3)] = 0u;
    __syncthreads();

    // count this slab's cells (rows s in [ch*64, ch*64+64)), padded row stride
    int rlo = ch << 6;
    for (int e = tid; e < EPG; e += 512) {
        int s = esrc[g * EPG + e] & (NP - 1);
        int d = edst[g * EPG + e] & (NP - 1);
        int sr = s - rlo;
        if ((unsigned)sr < 64u)
            atomicAdd(&cnt[sr * ASTW + (d >> 1)], (d & 1) ? 0x10000u : 1u);
    }
    __syncthreads();

    // sum(A^2) partial + in-place convert counts -> f16 (pads are 0 -> stay 0)
    float sumA2 = 0.f;
    for (int i = tid; i < 64 * ASTW; i += 512) {
        unsigned v = cnt[i];
        float m0 = (float)(v & 0xffffu), m1 = (float)(v >> 16);
        sumA2 += m0 * m0 + m1 * m1;
        union { unsigned u; _Float16 h[2]; } cv;
        cv.h[0] = (_Float16)m0; cv.h[1] = (_Float16)m1;
        cnt[i] = cv.u;
    }
    __syncthreads();

    const _Float16* Af = (const _Float16*)cnt;   // A slab [64][264] row-major

    // AS_slab = A_slab @ S : M=64 (nrow), N=64 (c, >=50 zero), K=256
    for (int t = wid * 2; t < wid * 2 + 2; ++t) {
        int mt = (t >> 2) << 4, nt = (t & 3) << 4;
        v4f acc = {0.f, 0.f, 0.f, 0.f};
        #pragma unroll
        for (int ks = 0; ks < 8; ++ks) {
            v8h af = *(const v8h*)&Af[(mt + l15) * ASTR + ks * 32 + fko];
            v8h bf = *(const v8h*)&ST[(nt + l15) * ASTR + ks * 32 + fko];
            acc = __builtin_amdgcn_mfma_f32_16x16x32_f16(af, bf, acc, 0, 0, 0);
        }
        int c = nt + l15;
        #pragma unroll
        for (int r = 0; r < 4; ++r)
            T1T[c * 72 + mt + quad * 4 + r] = (_Float16)acc[r];
    }
    __syncthreads();

    // Ap_slab[k][c] = sum_{n in slab} S[n][k] * AS[n][c] : M=k, N=c, K=64
    for (int t = wid * 2; t < wid * 2 + 2; ++t) {
        int mt = (t >> 2) << 4, nt = (t & 3) << 4;
        v4f acc = {0.f, 0.f, 0.f, 0.f};
        #pragma unroll
        for (int ks = 0; ks < 2; ++ks) {
            v8h af = *(const v8h*)&ST[(mt + l15) * ASTR + ch * 64 + ks * 32 + fko];
            v8h bf = *(const v8h*)&T1T[(nt + l15) * 72 + ks * 32 + fko];
            acc = __builtin_amdgcn_mfma_f32_16x16x32_f16(af, bf, acc, 0, 0, 0);
        }
        int c = nt + l15;
        if (c < KC) {
            #pragma unroll
            for (int r = 0; r < 4; ++r) {
                int k = mt + quad * 4 + r;
                if (k < KC)
                    g_Ap4[(size_t)blockIdx.x * (KC * KC) + k * KC + c] = acc[r];
            }
        }
    }

    float r = blockReduceN(sumA2, red, 8);
    if (tid == 0) atomicAdd(&ws[0], r);
}

// ---- K4: combine partials, ||G||^2, trace(Ap), dense GIN, classifier --------
__launch_bounds__(256, 3)
__global__ void k4_head(const float* __restrict__ W2a, const float* __restrict__ b2a,
                        const float* __restrict__ W2b, const float* __restrict__ b2b,
                        const float* __restrict__ Wl,  const float* __restrict__ bl,
                        float* __restrict__ out, float* __restrict__ ws)
{
    __shared__ __align__(16) float xpL[KC * HD];    // 12.8 KB  xp [k][d]
    __shared__ __align__(16) float Ap[KC * KC];     // 10 KB
    __shared__ __align__(16) float h2[KC * HD];     // 12.8 KB
    __shared__ __align__(16) float tt[KC * HD];     // 12.8 KB
    __shared__ float red[4];

    const int g = blockIdx.x, tid = threadIdx.x;
    const int lane = tid & 63, wid = tid >> 6;

    for (int i = tid; i < KC * HD; i += 256) {
        float v = 0.f;
        #pragma unroll
        for (int c = 0; c < NCH; ++c)
            v += g_PTp[(size_t)(g * NCH + c) * (KC * HD) + i];
        xpL[i] = v;
    }
    float sumG2 = 0.f, trL = 0.f;
    for (int i = tid; i < KC * KC; i += 256) {
        float v = 0.f, a = 0.f;
        #pragma unroll
        for (int c = 0; c < NCH; ++c) {
            v += g_Gp[(size_t)(g * NCH + c) * (KC * KC) + i];
            a += g_Ap4[(size_t)(g * 4 + c) * (KC * KC) + i];
        }
        sumG2 += v * v;
        Ap[i] = a;
        if (i % (KC + 1) == 0) trL += a;     // diagonal: i = k*(KC+1)
    }
    __syncthreads();

    // h2[k][d] = xp[k][d] + sum_l Ap[k][l] * xp[l][d]
    for (int k = wid; k < KC; k += 4) {
        float a = xpL[k * HD + lane];
        #pragma unroll
        for (int l = 0; l < KC; ++l)
            a += Ap[k * KC + l] * xpL[l * HD + lane];
        h2[k * HD + lane] = a;
    }
    __syncthreads();

    // t = relu(h2 @ W2a + b2a)
    {
        float wr[HD];
        #pragma unroll
        for (int d = 0; d < HD; ++d) wr[d] = W2a[d * HD + lane];
        float br = b2a[lane];
        for (int k = wid; k < KC; k += 4) {
            float a0 = br, a1 = 0.f, a2 = 0.f, a3 = 0.f;
            const float4* h4 = (const float4*)&h2[k * HD];
            #pragma unroll
            for (int i = 0; i < 16; ++i) {
                float4 v = h4[i];
                a0 += v.x * wr[4*i]; a1 += v.y * wr[4*i+1];
                a2 += v.z * wr[4*i+2]; a3 += v.w * wr[4*i+3];
            }
            tt[k * HD + lane] = fmaxf((a0 + a1) + (a2 + a3), 0.f);
        }
    }
    __syncthreads();

    // h3 = t @ W2b + b2b; fold mean over k and Wl into logits partials
    float l0 = 0.f, l1 = 0.f;
    {
        float wr[HD];
        #pragma unroll
        for (int j = 0; j < HD; ++j) wr[j] = W2b[j * HD + lane];
        float br = b2b[lane];
        float wl0 = Wl[lane * 2], wl1 = Wl[lane * 2 + 1];
        for (int k = wid; k < KC; k += 4) {
            float a0 = br, a1 = 0.f, a2 = 0.f, a3 = 0.f;
            const float4* t4 = (const float4*)&tt[k * HD];
            #pragma unroll
            for (int i = 0; i < 16; ++i) {
                float4 v = t4[i];
                a0 += v.x * wr[4*i]; a1 += v.y * wr[4*i+1];
                a2 += v.z * wr[4*i+2]; a3 += v.w * wr[4*i+3];
            }
            float a = (a0 + a1) + (a2 + a3);
            l0 += a * wl0; l1 += a * wl1;
        }
    }

    float rG2 = blockReduceN(sumG2, red, 4);
    float rTr = blockReduceN(trL, red, 4);
    float rl0 = blockReduceN(l0, red, 4);
    float rl1 = blockReduceN(l1, red, 4);
    if (tid == 0) {
        atomicAdd(&ws[3], rG2);
        atomicAdd(&ws[2], rTr);
        float g0 = bl[0] + rl0 * (1.f / KC);
        float g1 = bl[1] + rl1 * (1.f / KC);
        float mm = fmaxf(g0, g1);
        float lse = mm + logf(expf(g0 - mm) + expf(g1 - mm));
        out[2 * g]     = g0 - lse;
        out[2 * g + 1] = g1 - lse;
    }
}

extern "C" void kernel_launch(void* const* d_in, const int* in_sizes, int n_in,
                              void* d_out, int out_size, void* d_ws, size_t ws_size,
                              hipStream_t stream) {
    const float* x    = (const float*)d_in[0];
    const float* W1a  = (const float*)d_in[1];
    const float* b1a  = (const float*)d_in[2];
    const float* W1b  = (const float*)d_in[3];
    const float* b1b  = (const float*)d_in[4];
    const float* Wp   = (const float*)d_in[5];
    const float* bp   = (const float*)d_in[6];
    const float* W2a  = (const float*)d_in[7];
    const float* b2a  = (const float*)d_in[8];
    const float* W2b  = (const float*)d_in[9];
    const float* b2b  = (const float*)d_in[10];
    const float* Wl   = (const float*)d_in[11];
    const float* bl   = (const float*)d_in[12];
    const int*   eidx = (const int*)d_in[13];   // [2, E] int32
    float* out = (float*)d_out;
    float* ws  = (float*)d_ws;

    zero_ws<<<1, 64, 0, stream>>>(ws);
    k1a_sort<<<NG, 512, 0, stream>>>(eidx, eidx + ETOT, x);
    k2_mlp<<<NG * NCH, 512, 0, stream>>>(W1a, b1a, W1b, b1b, Wp, bp, ws);
    k3_fused<<<NG * 4, 512, 0, stream>>>(eidx, eidx + ETOT, ws);
    k4_head<<<NG, 256, 0, stream>>>(W2a, b2a, W2b, b2b, Wl, bl, out, ws);
    finalize_k<<<1, 64, 0, stream>>>(ws, out);
}

// Round 12
// 358.290 us; speedup vs baseline: 1.4628x; 1.1567x over previous
//
#include <hip/hip_runtime.h>
#include <math.h>

// Problem constants (from reference)
#define NG   1024        // graphs
#define NP   256         // nodes per graph
#define EPG  4096        // edges per graph
#define ETOT 4194304     // total edges
#define NTOT (NG * NP)   // 262144 nodes
#define FIN  7
#define HD   64
#define KC   50
#define CHK  64          // rows per K2 chunk
#define NCH  4           // chunks per graph
#define FST  72          // f16 LDS row stride in k2 (144 B rows, 16B-aligned)
#define ASTR 264         // k3 A/ST f16 row stride: 132 words = 4 mod 32 (2-way free)
#define ASTW 132         // ASTR in u32 words

// NOTE (R2): __launch_bounds__ 2nd arg acts as CUDA-style min BLOCKS/CU.
// NOTE (R3): LDS atomic scatter was 1215 us -> counting-sort gather.
// NOTE (R4): persistent per-lane arrays spill at the VGPR cap -> wave-row regs.
// NOTE (R5): GEMV-style phases are latency-bound -> f16 MFMA for k2 GEMMs.
// NOTE (R8): f16 scalar gathers add a cvt per element -> regressed.
// NOTE (R10/R11): dense-A slab + MFMA; stride 264 kills the 16-way conflicts.
// NOTE (R12): 4 slab-blocks/graph re-read all edges + full S^T (4x redundant,
// 104 MB of 117 MB FETCH). -> one 1024-thread block per graph: stage S^T and
// edges ONCE, loop 4 slabs, accumulate Ap tile in registers across slabs
// (16 waves = 16 tiles), write fp32 Ap + trace directly (g_Ap4 deleted).

typedef __attribute__((ext_vector_type(8))) _Float16 v8h;
typedef __attribute__((ext_vector_type(4))) float v4f;

// Inter-kernel intermediates as statics: no hipMalloc, graph-capture safe.
// Every element is rewritten each launch before being read.
__device__ float g_xagg[NTOT * 8];                  // x+agg, padded to 8
__device__ _Float16 g_ShT[(size_t)NG * KC * 256];   // S^T per graph [k][n], f16
__device__ float g_PTp[(size_t)NG * NCH * KC * HD]; // xp partials [k][d]
__device__ float g_Gp[(size_t)NG * NCH * KC * KC];  // G partials [k][c]
__device__ float g_Ap[(size_t)NG * KC * KC];        // Ap [k][c] fp32

__global__ void zero_ws(float* ws) {
    if (threadIdx.x < 4) ws[threadIdx.x] = 0.f;
}

// ws[0]=sumA2, ws[1]=sum S logS, ws[2]=trace(Ap)=sum(A.SSt), ws[3]=||G||^2
__global__ void finalize_k(const float* __restrict__ ws, float* __restrict__ out) {
    if (threadIdx.x == 0) {
        float num = ws[0] - 2.f * ws[2] + ws[3];
        float link = sqrtf(fmaxf(num, 0.f)) / 67108864.0f;   // / (B*n*n)
        float ent  = -ws[1] / 262144.0f;                     // / N
        out[2048] = link + ent;
    }
}

__device__ __forceinline__ float blockReduceN(float v, float* red, int nw) {
    __syncthreads();
    #pragma unroll
    for (int o = 32; o > 0; o >>= 1) v += __shfl_down(v, o);
    if ((threadIdx.x & 63) == 0) red[threadIdx.x >> 6] = v;
    __syncthreads();
    float r = 0.f;
    if (threadIdx.x == 0) {
        for (int i = 0; i < nw; ++i) r += red[i];
    }
    return r;
}

// ---- K1a: di counting sort + gather GIN aggregation -------------------------
// LDS ~25 KB -> 3 blocks/CU
__launch_bounds__(512, 3)
__global__ void k1a_sort(const int* __restrict__ esrc, const int* __restrict__ edst,
                         const float* __restrict__ x)
{
    __shared__ unsigned short cells[EPG];       // 8 KB
    __shared__ unsigned char ssi[EPG];          // 4 KB  (di-sorted si)
    __shared__ float xt8[NP * 8];               // 8 KB  (x, stride 8, pad 0)
    __shared__ unsigned int hist_di[256], cur_di[256];
    __shared__ unsigned int roff_di[NP + 1];

    const int g = blockIdx.x, tid = threadIdx.x;
    const int lane = tid & 63, wid = tid >> 6;

    if (tid < 256) hist_di[tid] = 0u;
    __syncthreads();

    for (int e = tid; e < EPG; e += 512) {
        int s = esrc[g * EPG + e] & (NP - 1);
        int d = edst[g * EPG + e] & (NP - 1);
        cells[e] = (unsigned short)((s << 8) | d);
        atomicAdd(&hist_di[d], 1u);
    }
    for (int i = tid; i < NP * 8; i += 512) {
        int n = i >> 3, f = i & 7;
        xt8[i] = (f < FIN) ? x[g * NP * FIN + n * FIN + f] : 0.f;
    }
    __syncthreads();

    // exclusive scan (wave 0)
    if (wid == 0) {
        unsigned carry = 0;
        for (int c = 0; c < 4; ++c) {
            unsigned v = hist_di[c * 64 + lane];
            unsigned s = v;
            #pragma unroll
            for (int o = 1; o < 64; o <<= 1) {
                unsigned t = __shfl_up(s, o);
                if (lane >= o) s += t;
            }
            unsigned excl = s - v + carry;
            roff_di[c * 64 + lane] = excl;
            cur_di[c * 64 + lane] = excl;
            carry += __shfl(s, 63);
        }
        if (lane == 0) roff_di[NP] = EPG;
    }
    __syncthreads();

    for (int e = tid; e < EPG; e += 512) {
        int c = cells[e]; int si = c >> 8, di = c & 255;
        unsigned p2 = atomicAdd(&cur_di[di], 1u);
        ssi[p2] = (unsigned char)si;
    }
    __syncthreads();

    // gather agg: 8 lanes per node (f = lane&7), write x+agg
    {
        const int gidx = tid >> 3, f = tid & 7;
        for (int n = gidx; n < NP; n += 64) {
            int beg = roff_di[n], end = roff_di[n + 1];
            float a = xt8[n * 8 + f];
            for (int e = beg; e < end; ++e)
                a += xt8[ssi[e] * 8 + f];
            g_xagg[g * NP * 8 + n * 8 + f] = a;
        }
    }
}

// ---- K2: MFMA f16 — MLP1, h-GEMM, P-GEMM, softmax, xp/G-GEMMs ---------------
__launch_bounds__(512, 2)
__global__ void k2_mlp(const float* __restrict__ W1a, const float* __restrict__ b1a,
                       const float* __restrict__ W1b, const float* __restrict__ b1b,
                       const float* __restrict__ Wp,  const float* __restrict__ bp,
                       float* __restrict__ ws)
{
    __shared__ __align__(16) float xt[CHK * 8];          // 2 KB
    __shared__ __align__(16) _Float16 t1b[CHK * FST];    // 9.2 KB  t1   [n][j]
    __shared__ __align__(16) _Float16 W1bT[HD * FST];    // 9.2 KB  W1b^T[d][j]
    __shared__ __align__(16) _Float16 WpT[HD * FST];     // 9.2 KB  Wp^T [k][d]
    __shared__ __align__(16) _Float16 hN[CHK * FST];     // 9.2 KB  h    [n][d]
    __shared__ __align__(16) _Float16 hT[HD * FST];      // 9.2 KB  h^T  [d][n]
    __shared__ __align__(16) _Float16 StT[HD * FST];     // 9.2 KB  S^T  [k][n]
    __shared__ __align__(16) float Pf[CHK * 66];         // 16.9 KB P    [n][k]
    __shared__ float red[8];

    const int b = blockIdx.x, rbase = b * CHK, tid = threadIdx.x;
    const int g = b >> 2, ch = b & 3;
    const int lane = tid & 63, wid = tid >> 6;
    const int l15 = lane & 15, quad = lane >> 4;
    const int fko = quad * 8;

    xt[tid] = g_xagg[rbase * 8 + tid];
    for (int i = tid; i < HD * HD; i += 512) {
        int j = i >> 6, d = i & 63;
        W1bT[d * FST + j] = (_Float16)W1b[i];
    }
    for (int i = tid; i < HD * KC; i += 512) {
        int d = i / KC, k = i - d * KC;
        WpT[k * FST + d] = (_Float16)Wp[i];
    }
    __syncthreads();

    // t1 = relu((x+agg) @ W1a + b1a)
    {
        float w1r[FIN];
        #pragma unroll
        for (int f = 0; f < FIN; ++f) w1r[f] = W1a[f * HD + lane];
        float br = b1a[lane];
        for (int n = wid; n < CHK; n += 8) {
            float a = br;
            #pragma unroll
            for (int f = 0; f < FIN; ++f) a += xt[n * 8 + f] * w1r[f];
            t1b[n * FST + lane] = (_Float16)fmaxf(a, 0.f);
        }
    }
    __syncthreads();

    // h = t1 @ W1b + b1b
    for (int t = wid * 2; t < wid * 2 + 2; ++t) {
        int mt = (t >> 2) << 4, nt = (t & 3) << 4;
        v4f acc = {0.f, 0.f, 0.f, 0.f};
        #pragma unroll
        for (int ks = 0; ks < 2; ++ks) {
            v8h af = *(const v8h*)&t1b[(mt + l15) * FST + ks * 32 + fko];
            v8h bf = *(const v8h*)&W1bT[(nt + l15) * FST + ks * 32 + fko];
            acc = __builtin_amdgcn_mfma_f32_16x16x32_f16(af, bf, acc, 0, 0, 0);
        }
        int d = nt + l15;
        float bv = b1b[d];
        #pragma unroll
        for (int r = 0; r < 4; ++r) {
            int m = mt + quad * 4 + r;
            _Float16 hv = (_Float16)(acc[r] + bv);
            hN[m * FST + d] = hv;
            hT[d * FST + m] = hv;
        }
    }
    __syncthreads();

    // P = h @ Wp + bp
    for (int t = wid * 2; t < wid * 2 + 2; ++t) {
        int mt = (t >> 2) << 4, nt = (t & 3) << 4;
        v4f acc = {0.f, 0.f, 0.f, 0.f};
        #pragma unroll
        for (int ks = 0; ks < 2; ++ks) {
            v8h af = *(const v8h*)&hN[(mt + l15) * FST + ks * 32 + fko];
            v8h bf = *(const v8h*)&WpT[(nt + l15) * FST + ks * 32 + fko];
            acc = __builtin_amdgcn_mfma_f32_16x16x32_f16(af, bf, acc, 0, 0, 0);
        }
        int kcol = nt + l15;
        if (kcol < KC) {
            float bv = bp[kcol];
            #pragma unroll
            for (int r = 0; r < 4; ++r)
                Pf[(mt + quad * 4 + r) * 66 + kcol] = acc[r] + bv;
        }
    }
    __syncthreads();

    // softmax -> StT f16 [k][n], entropy partial
    float entL = 0.f;
    for (int n = wid; n < CHK; n += 8) {
        float a = (lane < KC) ? Pf[n * 66 + lane] : -INFINITY;
        float m = a;
        #pragma unroll
        for (int o = 32; o > 0; o >>= 1) m = fmaxf(m, __shfl_xor(m, o));
        float e = expf(a - m);
        float ss = e;
        #pragma unroll
        for (int o = 32; o > 0; o >>= 1) ss += __shfl_xor(ss, o);
        float s = e / ss;
        if (lane < KC) {
            StT[lane * FST + n] = (_Float16)s;
            entL += s * logf(s + 1e-15f);
        }
    }
    __syncthreads();

    // persist S^T chunk to g_ShT (coalesced u32 rows)
    for (int i = tid; i < KC * 32; i += 512) {
        int k = i >> 5, o = i & 31;     // o: u32 index within 64-col chunk
        unsigned w = *(const unsigned int*)&StT[k * FST + 2 * o];
        ((unsigned int*)g_ShT)[((size_t)g * KC + k) * 128 + ch * 32 + o] = w;
    }

    // xp = S^T h ; G = S^T S (fused, shared A-frag)
    for (int t = wid * 2; t < wid * 2 + 2; ++t) {
        int mt = (t >> 2) << 4, nt = (t & 3) << 4;
        v4f axp = {0.f, 0.f, 0.f, 0.f};
        v4f ag  = {0.f, 0.f, 0.f, 0.f};
        #pragma unroll
        for (int ks = 0; ks < 2; ++ks) {
            v8h af = *(const v8h*)&StT[(mt + l15) * FST + ks * 32 + fko];
            v8h bh = *(const v8h*)&hT[(nt + l15) * FST + ks * 32 + fko];
            v8h bs = *(const v8h*)&StT[(nt + l15) * FST + ks * 32 + fko];
            axp = __builtin_amdgcn_mfma_f32_16x16x32_f16(af, bh, axp, 0, 0, 0);
            ag  = __builtin_amdgcn_mfma_f32_16x16x32_f16(af, bs, ag, 0, 0, 0);
        }
        int col = nt + l15;
        #pragma unroll
        for (int r = 0; r < 4; ++r) {
            int row = mt + quad * 4 + r;
            if (row < KC) {
                g_PTp[(size_t)b * (KC * HD) + row * HD + col] = axp[r];
                if (col < KC)
                    g_Gp[(size_t)b * (KC * KC) + row * KC + col] = ag[r];
            }
        }
    }

    float r = blockReduceN(entL, red, 8);
    if (tid == 0) atomicAdd(&ws[1], r);
}

// ---- K3_fused: one block per graph (1024 thr), 4-slab loop ------------------
// S^T staged once, edges staged once, Ap tile accumulated in regs across
// slabs (16 waves = 16 tiles). LDS ~83 KB -> 1 block/CU (16 waves).
__launch_bounds__(1024, 1)
__global__ void k3_fused(const int* __restrict__ esrc, const int* __restrict__ edst,
                         float* __restrict__ ws)
{
    __shared__ unsigned int cnt[64 * ASTW];          // 33 KB; becomes f16 A[64][264]
    __shared__ __align__(16) _Float16 ST[64 * ASTR]; // 33 KB  S^T [k][n] padded
    __shared__ __align__(16) _Float16 T1T[64 * 72];  // 9 KB   AS^T [c][nrow]
    __shared__ unsigned short cells[EPG];            // 8 KB
    __shared__ float red[16];

    const int g = blockIdx.x, tid = threadIdx.x;
    const int lane = tid & 63, wid = tid >> 6;       // wid 0..15
    const int l15 = lane & 15, quad = lane >> 4, fko = quad * 8;
    const int mt = (wid >> 2) << 4, nt = (wid & 3) << 4;   // this wave's tile

    // stage S^T once (zero rows k>=50, zero col pads)
    for (int i = tid; i < 64 * 128; i += 1024) {
        int k = i >> 7, o = i & 127;
        ((unsigned int*)ST)[k * ASTW + o] = (k < KC)
            ? ((const unsigned int*)g_ShT)[((size_t)g * KC + k) * 128 + o] : 0u;
    }
    for (int i = tid; i < 64 * 4; i += 1024)
        ((unsigned int*)ST)[(i >> 2) * ASTW + 128 + (i & 3)] = 0u;
    // stage edges once
    for (int e = tid; e < EPG; e += 1024) {
        int s = esrc[g * EPG + e] & (NP - 1);
        int d = edst[g * EPG + e] & (NP - 1);
        cells[e] = (unsigned short)((s << 8) | d);
    }
    __syncthreads();

    float sumA2 = 0.f;
    v4f ap = {0.f, 0.f, 0.f, 0.f};                   // Ap tile acc across slabs

    for (int ch = 0; ch < 4; ++ch) {
        // zero counts
        for (int i = tid; i < 64 * ASTW; i += 1024) cnt[i] = 0u;
        __syncthreads();

        // count this slab's cells (rows s in [ch*64, ch*64+64))
        int rlo = ch << 6;
        for (int e = tid; e < EPG; e += 1024) {
            int c = cells[e];
            int sr = (c >> 8) - rlo;
            if ((unsigned)sr < 64u) {
                int d = c & 255;
                atomicAdd(&cnt[sr * ASTW + (d >> 1)], (d & 1) ? 0x10000u : 1u);
            }
        }
        __syncthreads();

        // sum(A^2) partial + in-place convert counts -> f16 (pads stay 0)
        for (int i = tid; i < 64 * ASTW; i += 1024) {
            unsigned v = cnt[i];
            float m0 = (float)(v & 0xffffu), m1 = (float)(v >> 16);
            sumA2 += m0 * m0 + m1 * m1;
            union { unsigned u; _Float16 h[2]; } cv;
            cv.h[0] = (_Float16)m0; cv.h[1] = (_Float16)m1;
            cnt[i] = cv.u;
        }
        __syncthreads();

        const _Float16* Af = (const _Float16*)cnt;   // A slab [64][264]

        // AS_slab = A_slab @ S : 16 tiles, 1 per wave
        {
            v4f acc = {0.f, 0.f, 0.f, 0.f};
            #pragma unroll
            for (int ks = 0; ks < 8; ++ks) {
                v8h af = *(const v8h*)&Af[(mt + l15) * ASTR + ks * 32 + fko];
                v8h bf = *(const v8h*)&ST[(nt + l15) * ASTR + ks * 32 + fko];
                acc = __builtin_amdgcn_mfma_f32_16x16x32_f16(af, bf, acc, 0, 0, 0);
            }
            int c = nt + l15;
            #pragma unroll
            for (int r = 0; r < 4; ++r)
                T1T[c * 72 + mt + quad * 4 + r] = (_Float16)acc[r];
        }
        __syncthreads();

        // Ap[k][c] += S_slab^T @ AS_slab : accumulate tile in regs
        #pragma unroll
        for (int ks = 0; ks < 2; ++ks) {
            v8h af = *(const v8h*)&ST[(mt + l15) * ASTR + (ch << 6) + ks * 32 + fko];
            v8h bf = *(const v8h*)&T1T[(nt + l15) * 72 + ks * 32 + fko];
            ap = __builtin_amdgcn_mfma_f32_16x16x32_f16(af, bf, ap, 0, 0, 0);
        }
        __syncthreads();    // T1T/cnt reused next slab
    }

    // write Ap fp32; trace accumulates sum(A .* SSt)
    float tr = 0.f;
    {
        int c = nt + l15;
        #pragma unroll
        for (int r = 0; r < 4; ++r) {
            int k = mt + quad * 4 + r;
            if (k < KC && c < KC) {
                g_Ap[(size_t)g * (KC * KC) + k * KC + c] = ap[r];
                if (k == c) tr += ap[r];
            }
        }
    }

    float rA = blockReduceN(sumA2, red, 16);
    float rT = blockReduceN(tr, red, 16);
    if (tid == 0) {
        atomicAdd(&ws[0], rA);
        atomicAdd(&ws[2], rT);
    }
}

// ---- K4: combine partials, ||G||^2, dense GIN, classifier -------------------
__launch_bounds__(256, 3)
__global__ void k4_head(const float* __restrict__ W2a, const float* __restrict__ b2a,
                        const float* __restrict__ W2b, const float* __restrict__ b2b,
                        const float* __restrict__ Wl,  const float* __restrict__ bl,
                        float* __restrict__ out, float* __restrict__ ws)
{
    __shared__ __align__(16) float xpL[KC * HD];    // 12.8 KB  xp [k][d]
    __shared__ __align__(16) float Ap[KC * KC];     // 10 KB
    __shared__ __align__(16) float h2[KC * HD];     // 12.8 KB
    __shared__ __align__(16) float tt[KC * HD];     // 12.8 KB
    __shared__ float red[4];

    const int g = blockIdx.x, tid = threadIdx.x;
    const int lane = tid & 63, wid = tid >> 6;

    for (int i = tid; i < KC * HD; i += 256) {
        float v = 0.f;
        #pragma unroll
        for (int c = 0; c < NCH; ++c)
            v += g_PTp[(size_t)(g * NCH + c) * (KC * HD) + i];
        xpL[i] = v;
    }
    float sumG2 = 0.f;
    for (int i = tid; i < KC * KC; i += 256) {
        float v = 0.f;
        #pragma unroll
        for (int c = 0; c < NCH; ++c)
            v += g_Gp[(size_t)(g * NCH + c) * (KC * KC) + i];
        sumG2 += v * v;
        Ap[i] = g_Ap[(size_t)g * (KC * KC) + i];
    }
    __syncthreads();

    // h2[k][d] = xp[k][d] + sum_l Ap[k][l] * xp[l][d]
    for (int k = wid; k < KC; k += 4) {
        float a = xpL[k * HD + lane];
        #pragma unroll
        for (int l = 0; l < KC; ++l)
            a += Ap[k * KC + l] * xpL[l * HD + lane];
        h2[k * HD + lane] = a;
    }
    __syncthreads();

    // t = relu(h2 @ W2a + b2a)
    {
        float wr[HD];
        #pragma unroll
        for (int d = 0; d < HD; ++d) wr[d] = W2a[d * HD + lane];
        float br = b2a[lane];
        for (int k = wid; k < KC; k += 4) {
            float a0 = br, a1 = 0.f, a2 = 0.f, a3 = 0.f;
            const float4* h4 = (const float4*)&h2[k * HD];
            #pragma unroll
            for (int i = 0; i < 16; ++i) {
                float4 v = h4[i];
                a0 += v.x * wr[4*i]; a1 += v.y * wr[4*i+1];
                a2 += v.z * wr[4*i+2]; a3 += v.w * wr[4*i+3];
            }
            tt[k * HD + lane] = fmaxf((a0 + a1) + (a2 + a3), 0.f);
        }
    }
    __syncthreads();

    // h3 = t @ W2b + b2b; fold mean over k and Wl into logits partials
    float l0 = 0.f, l1 = 0.f;
    {
        float wr[HD];
        #pragma unroll
        for (int j = 0; j < HD; ++j) wr[j] = W2b[j * HD + lane];
        float br = b2b[lane];
        float wl0 = Wl[lane * 2], wl1 = Wl[lane * 2 + 1];
        for (int k = wid; k < KC; k += 4) {
            float a0 = br, a1 = 0.f, a2 = 0.f, a3 = 0.f;
            const float4* t4 = (const float4*)&tt[k * HD];
            #pragma unroll
            for (int i = 0; i < 16; ++i) {
                float4 v = t4[i];
                a0 += v.x * wr[4*i]; a1 += v.y * wr[4*i+1];
                a2 += v.z * wr[4*i+2]; a3 += v.w * wr[4*i+3];
            }
            float a = (a0 + a1) + (a2 + a3);
            l0 += a * wl0; l1 += a * wl1;
        }
    }

    float rG2 = blockReduceN(sumG2, red, 4);
    float rl0 = blockReduceN(l0, red, 4);
    float rl1 = blockReduceN(l1, red, 4);
    if (tid == 0) {
        atomicAdd(&ws[3], rG2);
        float g0 = bl[0] + rl0 * (1.f / KC);
        float g1 = bl[1] + rl1 * (1.f / KC);
        float mm = fmaxf(g0, g1);
        float lse = mm + logf(expf(g0 - mm) + expf(g1 - mm));
        out[2 * g]     = g0 - lse;
        out[2 * g + 1] = g1 - lse;
    }
}

extern "C" void kernel_launch(void* const* d_in, const int* in_sizes, int n_in,
                              void* d_out, int out_size, void* d_ws, size_t ws_size,
                              hipStream_t stream) {
    const float* x    = (const float*)d_in[0];
    const float* W1a  = (const float*)d_in[1];
    const float* b1a  = (const float*)d_in[2];
    const float* W1b  = (const float*)d_in[3];
    const float* b1b  = (const float*)d_in[4];
    const float* Wp   = (const float*)d_in[5];
    const float* bp   = (const float*)d_in[6];
    const float* W2a  = (const float*)d_in[7];
    const float* b2a  = (const float*)d_in[8];
    const float* W2b  = (const float*)d_in[9];
    const float* b2b  = (const float*)d_in[10];
    const float* Wl   = (const float*)d_in[11];
    const float* bl   = (const float*)d_in[12];
    const int*   eidx = (const int*)d_in[13];   // [2, E] int32
    float* out = (float*)d_out;
    float* ws  = (float*)d_ws;

    zero_ws<<<1, 64, 0, stream>>>(ws);
    k1a_sort<<<NG, 512, 0, stream>>>(eidx, eidx + ETOT, x);
    k2_mlp<<<NG * NCH, 512, 0, stream>>>(W1a, b1a, W1b, b1b, Wp, bp, ws);
    k3_fused<<<NG, 1024, 0, stream>>>(eidx, eidx + ETOT, ws);
    k4_head<<<NG, 256, 0, stream>>>(W2a, b2a, W2b, b2b, Wl, bl, out, ws);
    finalize_k<<<1, 64, 0, stream>>>(ws, out);
}

// Round 13
// 355.785 us; speedup vs baseline: 1.4731x; 1.0070x over previous
//
#include <hip/hip_runtime.h>
#include <math.h>

// Problem constants (from reference)
#define NG   1024        // graphs
#define NP   256         // nodes per graph
#define EPG  4096        // edges per graph
#define ETOT 4194304     // total edges
#define NTOT (NG * NP)   // 262144 nodes
#define FIN  7
#define HD   64
#define KC   50
#define CHK  64          // rows per K2 chunk
#define NCH  4           // chunks per graph
#define FST  72          // f16 LDS row stride in k2 (144 B rows, 16B-aligned)
#define ASTR 264         // k3 f16 row stride: 132 words = 4 mod 32 (2-way free)
#define ASTW 132         // ASTR in u32 words

// NOTE (R2): __launch_bounds__ 2nd arg acts as CUDA-style min BLOCKS/CU.
// NOTE (R3): LDS atomic scatter -> counting-sort gather.
// NOTE (R4): persistent per-lane arrays spill at the VGPR cap -> wave-row regs.
// NOTE (R5): GEMV-style phases are latency-bound -> f16 MFMA GEMMs.
// NOTE (R8): f16 scalar gathers add a cvt per element -> regressed.
// NOTE (R10/R11): dense-A slabs + MFMA; stride 264 kills 16-way conflicts.
// NOTE (R12): one 1024-thread block/graph for k3; stage once, reg-accumulate.
// NOTE (R13): k2 was VALU-bound on redundancy: per-block weight cvt (x4096),
// xp/G partial writes (93 MB). -> weights preconverted once (kw_conv);
// xp/G moved into k3 (full S^T already there; h^T passed via global f16);
// ||G||^2 collapsed to scalar in k3. g_PTp/g_Gp deleted.

typedef __attribute__((ext_vector_type(8))) _Float16 v8h;
typedef __attribute__((ext_vector_type(4))) float v4f;

// Inter-kernel intermediates as statics: no hipMalloc, graph-capture safe.
// Every element is rewritten each launch before being read.
__device__ float g_xagg[NTOT * 8];                  // x+agg, padded to 8
__device__ _Float16 g_W1bT[HD * HD];                // W1b^T [d][j] f16
__device__ _Float16 g_WpT[HD * HD];                 // Wp^T  [k][d] f16 (k>=50 = 0)
__device__ _Float16 g_ShT[(size_t)NG * KC * 256];   // S^T per graph [k][n], f16
__device__ _Float16 g_hT[(size_t)NG * HD * 256];    // h^T per graph [d][n], f16
__device__ float g_xp[(size_t)NG * KC * HD];        // xp [k][d] fp32
__device__ float g_Ap[(size_t)NG * KC * KC];        // Ap [k][c] fp32

__global__ void zero_ws(float* ws) {
    if (threadIdx.x < 4) ws[threadIdx.x] = 0.f;
}

// one-shot weight f16 preconversion (same work every launch; capture-safe)
__global__ void kw_conv(const float* __restrict__ W1b, const float* __restrict__ Wp) {
    const int tid = threadIdx.x;
    for (int i = tid; i < HD * HD; i += 1024) {
        int d = i >> 6, j = i & 63;
        g_W1bT[i] = (_Float16)W1b[j * HD + d];
    }
    for (int i = tid; i < HD * HD; i += 1024) {
        int k = i >> 6, d = i & 63;
        g_WpT[i] = (k < KC) ? (_Float16)Wp[d * KC + k] : (_Float16)0.f;
    }
}

// ws[0]=sumA2, ws[1]=sum S logS, ws[2]=trace(Ap)=sum(A.SSt), ws[3]=||G||^2
__global__ void finalize_k(const float* __restrict__ ws, float* __restrict__ out) {
    if (threadIdx.x == 0) {
        float num = ws[0] - 2.f * ws[2] + ws[3];
        float link = sqrtf(fmaxf(num, 0.f)) / 67108864.0f;   // / (B*n*n)
        float ent  = -ws[1] / 262144.0f;                     // / N
        out[2048] = link + ent;
    }
}

__device__ __forceinline__ float blockReduceN(float v, float* red, int nw) {
    __syncthreads();
    #pragma unroll
    for (int o = 32; o > 0; o >>= 1) v += __shfl_down(v, o);
    if ((threadIdx.x & 63) == 0) red[threadIdx.x >> 6] = v;
    __syncthreads();
    float r = 0.f;
    if (threadIdx.x == 0) {
        for (int i = 0; i < nw; ++i) r += red[i];
    }
    return r;
}

// ---- K1a: di counting sort + gather GIN aggregation -------------------------
// LDS ~25 KB -> 3 blocks/CU
__launch_bounds__(512, 3)
__global__ void k1a_sort(const int* __restrict__ esrc, const int* __restrict__ edst,
                         const float* __restrict__ x)
{
    __shared__ unsigned short cells[EPG];       // 8 KB
    __shared__ unsigned char ssi[EPG];          // 4 KB  (di-sorted si)
    __shared__ float xt8[NP * 8];               // 8 KB  (x, stride 8, pad 0)
    __shared__ unsigned int hist_di[256], cur_di[256];
    __shared__ unsigned int roff_di[NP + 1];

    const int g = blockIdx.x, tid = threadIdx.x;
    const int lane = tid & 63, wid = tid >> 6;

    if (tid < 256) hist_di[tid] = 0u;
    __syncthreads();

    for (int e = tid; e < EPG; e += 512) {
        int s = esrc[g * EPG + e] & (NP - 1);
        int d = edst[g * EPG + e] & (NP - 1);
        cells[e] = (unsigned short)((s << 8) | d);
        atomicAdd(&hist_di[d], 1u);
    }
    for (int i = tid; i < NP * 8; i += 512) {
        int n = i >> 3, f = i & 7;
        xt8[i] = (f < FIN) ? x[g * NP * FIN + n * FIN + f] : 0.f;
    }
    __syncthreads();

    // exclusive scan (wave 0)
    if (wid == 0) {
        unsigned carry = 0;
        for (int c = 0; c < 4; ++c) {
            unsigned v = hist_di[c * 64 + lane];
            unsigned s = v;
            #pragma unroll
            for (int o = 1; o < 64; o <<= 1) {
                unsigned t = __shfl_up(s, o);
                if (lane >= o) s += t;
            }
            unsigned excl = s - v + carry;
            roff_di[c * 64 + lane] = excl;
            cur_di[c * 64 + lane] = excl;
            carry += __shfl(s, 63);
        }
        if (lane == 0) roff_di[NP] = EPG;
    }
    __syncthreads();

    for (int e = tid; e < EPG; e += 512) {
        int c = cells[e]; int si = c >> 8, di = c & 255;
        unsigned p2 = atomicAdd(&cur_di[di], 1u);
        ssi[p2] = (unsigned char)si;
    }
    __syncthreads();

    // gather agg: 8 lanes per node (f = lane&7), write x+agg
    {
        const int gidx = tid >> 3, f = tid & 7;
        for (int n = gidx; n < NP; n += 64) {
            int beg = roff_di[n], end = roff_di[n + 1];
            float a = xt8[n * 8 + f];
            for (int e = beg; e < end; ++e)
                a += xt8[ssi[e] * 8 + f];
            g_xagg[g * NP * 8 + n * 8 + f] = a;
        }
    }
}

// ---- K2: MFMA f16 — MLP1, h-GEMM, P-GEMM, softmax; emits S^T, h^T -----------
__launch_bounds__(512, 2)
__global__ void k2_mlp(const float* __restrict__ W1a, const float* __restrict__ b1a,
                       const float* __restrict__ b1b, const float* __restrict__ bp,
                       float* __restrict__ ws)
{
    __shared__ __align__(16) float xt[CHK * 8];          // 2 KB
    __shared__ __align__(16) _Float16 t1b[CHK * FST];    // 9.2 KB  t1   [n][j]
    __shared__ __align__(16) _Float16 W1bT[HD * FST];    // 9.2 KB  W1b^T[d][j]
    __shared__ __align__(16) _Float16 WpT[HD * FST];     // 9.2 KB  Wp^T [k][d]
    __shared__ __align__(16) _Float16 hN[CHK * FST];     // 9.2 KB  h    [n][d]
    __shared__ __align__(16) _Float16 hT[HD * FST];      // 9.2 KB  h^T  [d][n]
    __shared__ __align__(16) _Float16 StT[HD * FST];     // 9.2 KB  S^T  [k][n]
    __shared__ __align__(16) float Pf[CHK * 66];         // 16.9 KB P    [n][k]
    __shared__ float red[8];

    const int b = blockIdx.x, rbase = b * CHK, tid = threadIdx.x;
    const int g = b >> 2, ch = b & 3;
    const int lane = tid & 63, wid = tid >> 6;
    const int l15 = lane & 15, quad = lane >> 4;
    const int fko = quad * 8;

    xt[tid] = g_xagg[rbase * 8 + tid];
    // stage preconverted weights (u32 vector copies, no cvt)
    for (int i = tid; i < HD * 32; i += 512) {
        int r = i >> 5, o = i & 31;
        ((unsigned int*)W1bT)[r * 36 + o] = ((const unsigned int*)g_W1bT)[r * 32 + o];
        ((unsigned int*)WpT)[r * 36 + o]  = ((const unsigned int*)g_WpT)[r * 32 + o];
    }
    __syncthreads();

    // t1 = relu((x+agg) @ W1a + b1a)
    {
        float w1r[FIN];
        #pragma unroll
        for (int f = 0; f < FIN; ++f) w1r[f] = W1a[f * HD + lane];
        float br = b1a[lane];
        for (int n = wid; n < CHK; n += 8) {
            float a = br;
            #pragma unroll
            for (int f = 0; f < FIN; ++f) a += xt[n * 8 + f] * w1r[f];
            t1b[n * FST + lane] = (_Float16)fmaxf(a, 0.f);
        }
    }
    __syncthreads();

    // h = t1 @ W1b + b1b
    for (int t = wid * 2; t < wid * 2 + 2; ++t) {
        int mt = (t >> 2) << 4, nt = (t & 3) << 4;
        v4f acc = {0.f, 0.f, 0.f, 0.f};
        #pragma unroll
        for (int ks = 0; ks < 2; ++ks) {
            v8h af = *(const v8h*)&t1b[(mt + l15) * FST + ks * 32 + fko];
            v8h bf = *(const v8h*)&W1bT[(nt + l15) * FST + ks * 32 + fko];
            acc = __builtin_amdgcn_mfma_f32_16x16x32_f16(af, bf, acc, 0, 0, 0);
        }
        int d = nt + l15;
        float bv = b1b[d];
        #pragma unroll
        for (int r = 0; r < 4; ++r) {
            int m = mt + quad * 4 + r;
            _Float16 hv = (_Float16)(acc[r] + bv);
            hN[m * FST + d] = hv;
            hT[d * FST + m] = hv;
        }
    }
    __syncthreads();

    // persist h^T chunk (coalesced u32)
    for (int i = tid; i < HD * 32; i += 512) {
        int d = i >> 5, o = i & 31;
        unsigned w = *(const unsigned int*)&hT[d * FST + 2 * o];
        ((unsigned int*)g_hT)[((size_t)g * HD + d) * 128 + ch * 32 + o] = w;
    }

    // P = h @ Wp + bp
    for (int t = wid * 2; t < wid * 2 + 2; ++t) {
        int mt = (t >> 2) << 4, nt = (t & 3) << 4;
        v4f acc = {0.f, 0.f, 0.f, 0.f};
        #pragma unroll
        for (int ks = 0; ks < 2; ++ks) {
            v8h af = *(const v8h*)&hN[(mt + l15) * FST + ks * 32 + fko];
            v8h bf = *(const v8h*)&WpT[(nt + l15) * FST + ks * 32 + fko];
            acc = __builtin_amdgcn_mfma_f32_16x16x32_f16(af, bf, acc, 0, 0, 0);
        }
        int kcol = nt + l15;
        if (kcol < KC) {
            float bv = bp[kcol];
            #pragma unroll
            for (int r = 0; r < 4; ++r)
                Pf[(mt + quad * 4 + r) * 66 + kcol] = acc[r] + bv;
        }
    }
    __syncthreads();

    // softmax -> StT f16 [k][n], entropy partial
    float entL = 0.f;
    for (int n = wid; n < CHK; n += 8) {
        float a = (lane < KC) ? Pf[n * 66 + lane] : -INFINITY;
        float m = a;
        #pragma unroll
        for (int o = 32; o > 0; o >>= 1) m = fmaxf(m, __shfl_xor(m, o));
        float e = expf(a - m);
        float ss = e;
        #pragma unroll
        for (int o = 32; o > 0; o >>= 1) ss += __shfl_xor(ss, o);
        float s = e / ss;
        if (lane < KC) {
            StT[lane * FST + n] = (_Float16)s;
            entL += s * logf(s + 1e-15f);
        }
    }
    __syncthreads();

    // persist S^T chunk (coalesced u32)
    for (int i = tid; i < KC * 32; i += 512) {
        int k = i >> 5, o = i & 31;
        unsigned w = *(const unsigned int*)&StT[k * FST + 2 * o];
        ((unsigned int*)g_ShT)[((size_t)g * KC + k) * 128 + ch * 32 + o] = w;
    }

    float r = blockReduceN(entL, red, 8);
    if (tid == 0) atomicAdd(&ws[1], r);
}

// ---- K3_fused: per-graph dense-A slabs + MFMA AS/Ap/xp/G + scalars ----------
// One 1024-thread block per graph; S^T, h^T, edges staged once; Ap/xp/G tiles
// accumulated in regs across 4 slabs (16 waves = 16 tiles each).
// LDS ~119 KB -> 1 block/CU (16 waves).
__launch_bounds__(1024, 1)
__global__ void k3_fused(const int* __restrict__ esrc, const int* __restrict__ edst,
                         float* __restrict__ ws)
{
    __shared__ unsigned int cnt[64 * ASTW];          // 33 KB; becomes f16 A[64][264]
    __shared__ __align__(16) _Float16 ST[64 * ASTR]; // 33 KB  S^T [k][n] padded
    __shared__ __align__(16) _Float16 HT[64 * ASTR]; // 33 KB  h^T [d][n] padded
    __shared__ __align__(16) _Float16 T1T[64 * 72];  // 9 KB   AS^T [c][nrow]
    __shared__ unsigned short cells[EPG];            // 8 KB
    __shared__ float red[16];

    const int g = blockIdx.x, tid = threadIdx.x;
    const int lane = tid & 63, wid = tid >> 6;       // wid 0..15
    const int l15 = lane & 15, quad = lane >> 4, fko = quad * 8;
    const int mt = (wid >> 2) << 4, nt = (wid & 3) << 4;   // this wave's tile

    // stage S^T and h^T once (zero S^T rows k>=50; zero col pads on both)
    for (int i = tid; i < 64 * 128; i += 1024) {
        int k = i >> 7, o = i & 127;
        ((unsigned int*)ST)[k * ASTW + o] = (k < KC)
            ? ((const unsigned int*)g_ShT)[((size_t)g * KC + k) * 128 + o] : 0u;
        ((unsigned int*)HT)[k * ASTW + o] =
            ((const unsigned int*)g_hT)[((size_t)g * HD + k) * 128 + o];
    }
    for (int i = tid; i < 64 * 4; i += 1024) {
        ((unsigned int*)ST)[(i >> 2) * ASTW + 128 + (i & 3)] = 0u;
        ((unsigned int*)HT)[(i >> 2) * ASTW + 128 + (i & 3)] = 0u;
    }
    // stage edges once
    for (int e = tid; e < EPG; e += 1024) {
        int s = esrc[g * EPG + e] & (NP - 1);
        int d = edst[g * EPG + e] & (NP - 1);
        cells[e] = (unsigned short)((s << 8) | d);
    }
    __syncthreads();

    float sumA2 = 0.f;
    v4f ap  = {0.f, 0.f, 0.f, 0.f};                  // Ap tile
    v4f axp = {0.f, 0.f, 0.f, 0.f};                  // xp tile
    v4f ag  = {0.f, 0.f, 0.f, 0.f};                  // G tile

    for (int ch = 0; ch < 4; ++ch) {
        for (int i = tid; i < 64 * ASTW; i += 1024) cnt[i] = 0u;
        __syncthreads();

        // count this slab's cells (rows s in [ch*64, ch*64+64))
        int rlo = ch << 6;
        for (int e = tid; e < EPG; e += 1024) {
            int c = cells[e];
            int sr = (c >> 8) - rlo;
            if ((unsigned)sr < 64u) {
                int d = c & 255;
                atomicAdd(&cnt[sr * ASTW + (d >> 1)], (d & 1) ? 0x10000u : 1u);
            }
        }
        __syncthreads();

        // sum(A^2) partial + in-place convert counts -> f16 (pads stay 0)
        for (int i = tid; i < 64 * ASTW; i += 1024) {
            unsigned v = cnt[i];
            float m0 = (float)(v & 0xffffu), m1 = (float)(v >> 16);
            sumA2 += m0 * m0 + m1 * m1;
            union { unsigned u; _Float16 h[2]; } cv;
            cv.h[0] = (_Float16)m0; cv.h[1] = (_Float16)m1;
            cnt[i] = cv.u;
        }
        __syncthreads();

        const _Float16* Af = (const _Float16*)cnt;   // A slab [64][264]

        // AS_slab = A_slab @ S : 16 tiles, 1 per wave
        {
            v4f acc = {0.f, 0.f, 0.f, 0.f};
            #pragma unroll
            for (int ks = 0; ks < 8; ++ks) {
                v8h af = *(const v8h*)&Af[(mt + l15) * ASTR + ks * 32 + fko];
                v8h bf = *(const v8h*)&ST[(nt + l15) * ASTR + ks * 32 + fko];
                acc = __builtin_amdgcn_mfma_f32_16x16x32_f16(af, bf, acc, 0, 0, 0);
            }
            int c = nt + l15;
            #pragma unroll
            for (int r = 0; r < 4; ++r)
                T1T[c * 72 + mt + quad * 4 + r] = (_Float16)acc[r];
        }
        __syncthreads();

        // Ap += S_slab^T @ AS_slab; xp += S_slab^T @ h_slab; G += S^T S (slab)
        #pragma unroll
        for (int ks = 0; ks < 2; ++ks) {
            int ko = (ch << 6) + ks * 32 + fko;
            v8h af = *(const v8h*)&ST[(mt + l15) * ASTR + ko];
            v8h bt = *(const v8h*)&T1T[(nt + l15) * 72 + ks * 32 + fko];
            v8h bh = *(const v8h*)&HT[(nt + l15) * ASTR + ko];
            v8h bs = *(const v8h*)&ST[(nt + l15) * ASTR + ko];
            ap  = __builtin_amdgcn_mfma_f32_16x16x32_f16(af, bt, ap, 0, 0, 0);
            axp = __builtin_amdgcn_mfma_f32_16x16x32_f16(af, bh, axp, 0, 0, 0);
            ag  = __builtin_amdgcn_mfma_f32_16x16x32_f16(af, bs, ag, 0, 0, 0);
        }
        __syncthreads();    // T1T/cnt reused next slab
    }

    // write xp, Ap; accumulate trace(Ap) and ||G||^2
    float tr = 0.f, g2 = 0.f;
    {
        int c = nt + l15;
        #pragma unroll
        for (int r = 0; r < 4; ++r) {
            int k = mt + quad * 4 + r;
            if (k < KC) {
                g_xp[(size_t)g * (KC * HD) + k * HD + c] = axp[r];
                if (c < KC) {
                    g_Ap[(size_t)g * (KC * KC) + k * KC + c] = ap[r];
                    if (k == c) tr += ap[r];
                    g2 += ag[r] * ag[r];
                }
            }
        }
    }

    float rA = blockReduceN(sumA2, red, 16);
    float rT = blockReduceN(tr, red, 16);
    float rG = blockReduceN(g2, red, 16);
    if (tid == 0) {
        atomicAdd(&ws[0], rA);
        atomicAdd(&ws[2], rT);
        atomicAdd(&ws[3], rG);
    }
}

// ---- K4: dense GIN + classifier ---------------------------------------------
__launch_bounds__(256, 3)
__global__ void k4_head(const float* __restrict__ W2a, const float* __restrict__ b2a,
                        const float* __restrict__ W2b, const float* __restrict__ b2b,
                        const float* __restrict__ Wl,  const float* __restrict__ bl,
                        float* __restrict__ out)
{
    __shared__ __align__(16) float xpL[KC * HD];    // 12.8 KB  xp [k][d]
    __shared__ __align__(16) float Ap[KC * KC];     // 10 KB
    __shared__ __align__(16) float h2[KC * HD];     // 12.8 KB
    __shared__ __align__(16) float tt[KC * HD];     // 12.8 KB
    __shared__ float red[4];

    const int g = blockIdx.x, tid = threadIdx.x;
    const int lane = tid & 63, wid = tid >> 6;

    for (int i = tid; i < KC * HD; i += 256)
        xpL[i] = g_xp[(size_t)g * (KC * HD) + i];
    for (int i = tid; i < KC * KC; i += 256)
        Ap[i] = g_Ap[(size_t)g * (KC * KC) + i];
    __syncthreads();

    // h2[k][d] = xp[k][d] + sum_l Ap[k][l] * xp[l][d]
    for (int k = wid; k < KC; k += 4) {
        float a = xpL[k * HD + lane];
        #pragma unroll
        for (int l = 0; l < KC; ++l)
            a += Ap[k * KC + l] * xpL[l * HD + lane];
        h2[k * HD + lane] = a;
    }
    __syncthreads();

    // t = relu(h2 @ W2a + b2a)
    {
        float wr[HD];
        #pragma unroll
        for (int d = 0; d < HD; ++d) wr[d] = W2a[d * HD + lane];
        float br = b2a[lane];
        for (int k = wid; k < KC; k += 4) {
            float a0 = br, a1 = 0.f, a2 = 0.f, a3 = 0.f;
            const float4* h4 = (const float4*)&h2[k * HD];
            #pragma unroll
            for (int i = 0; i < 16; ++i) {
                float4 v = h4[i];
                a0 += v.x * wr[4*i]; a1 += v.y * wr[4*i+1];
                a2 += v.z * wr[4*i+2]; a3 += v.w * wr[4*i+3];
            }
            tt[k * HD + lane] = fmaxf((a0 + a1) + (a2 + a3), 0.f);
        }
    }
    __syncthreads();

    // h3 = t @ W2b + b2b; fold mean over k and Wl into logits partials
    float l0 = 0.f, l1 = 0.f;
    {
        float wr[HD];
        #pragma unroll
        for (int j = 0; j < HD; ++j) wr[j] = W2b[j * HD + lane];
        float br = b2b[lane];
        float wl0 = Wl[lane * 2], wl1 = Wl[lane * 2 + 1];
        for (int k = wid; k < KC; k += 4) {
            float a0 = br, a1 = 0.f, a2 = 0.f, a3 = 0.f;
            const float4* t4 = (const float4*)&tt[k * HD];
            #pragma unroll
            for (int i = 0; i < 16; ++i) {
                float4 v = t4[i];
                a0 += v.x * wr[4*i]; a1 += v.y * wr[4*i+1];
                a2 += v.z * wr[4*i+2]; a3 += v.w * wr[4*i+3];
            }
            float a = (a0 + a1) + (a2 + a3);
            l0 += a * wl0; l1 += a * wl1;
        }
    }

    float rl0 = blockReduceN(l0, red, 4);
    float rl1 = blockReduceN(l1, red, 4);
    if (tid == 0) {
        float g0 = bl[0] + rl0 * (1.f / KC);
        float g1 = bl[1] + rl1 * (1.f / KC);
        float mm = fmaxf(g0, g1);
        float lse = mm + logf(expf(g0 - mm) + expf(g1 - mm));
        out[2 * g]     = g0 - lse;
        out[2 * g + 1] = g1 - lse;
    }
}

extern "C" void kernel_launch(void* const* d_in, const int* in_sizes, int n_in,
                              void* d_out, int out_size, void* d_ws, size_t ws_size,
                              hipStream_t stream) {
    const float* x    = (const float*)d_in[0];
    const float* W1a  = (const float*)d_in[1];
    const float* b1a  = (const float*)d_in[2];
    const float* W1b  = (const float*)d_in[3];
    const float* b1b  = (const float*)d_in[4];
    const float* Wp   = (const float*)d_in[5];
    const float* bp   = (const float*)d_in[6];
    const float* W2a  = (const float*)d_in[7];
    const float* b2a  = (const float*)d_in[8];
    const float* W2b  = (const float*)d_in[9];
    const float* b2b  = (const float*)d_in[10];
    const float* Wl   = (const float*)d_in[11];
    const float* bl   = (const float*)d_in[12];
    const int*   eidx = (const int*)d_in[13];   // [2, E] int32
    float* out = (float*)d_out;
    float* ws  = (float*)d_ws;

    zero_ws<<<1, 64, 0, stream>>>(ws);
    kw_conv<<<1, 1024, 0, stream>>>(W1b, Wp);
    k1a_sort<<<NG, 512, 0, stream>>>(eidx, eidx + ETOT, x);
    k2_mlp<<<NG * NCH, 512, 0, stream>>>(W1a, b1a, b1b, bp, ws);
    k3_fused<<<NG, 1024, 0, stream>>>(eidx, eidx + ETOT, ws);
    k4_head<<<NG, 256, 0, stream>>>(W2a, b2a, W2b, b2b, Wl, bl, out);
    finalize_k<<<1, 64, 0, stream>>>(ws, out);
}

// Round 14
// 339.705 us; speedup vs baseline: 1.5428x; 1.0473x over previous
//
#include <hip/hip_runtime.h>
#include <math.h>

// Problem constants (from reference)
#define NG   1024        // graphs
#define NP   256         // nodes per graph
#define EPG  4096        // edges per graph
#define ETOT 4194304     // total edges
#define NTOT (NG * NP)   // 262144 nodes
#define FIN  7
#define HD   64
#define KC   50
#define CHK  64          // rows per K2 chunk
#define NCH  4           // chunks per graph
#define FST  72          // f16 LDS row stride in k2 (144 B rows, 16B-aligned)
#define ASTR 264         // k3 f16 row stride: 132 words = 4 mod 32 (2-way free)
#define ASTW 132         // ASTR in u32 words

// NOTE (R2): __launch_bounds__ 2nd arg acts as CUDA-style min BLOCKS/CU.
// NOTE (R3): LDS atomic scatter -> counting-sort gather.
// NOTE (R4): persistent per-lane arrays spill at the VGPR cap -> wave-row regs.
// NOTE (R5): GEMV-style phases are latency-bound -> f16 MFMA GEMMs.
// NOTE (R8): f16 scalar gathers add a cvt per element -> regressed.
// NOTE (R10/R11): dense-A slabs + MFMA; stride 264 kills 16-way conflicts.
// NOTE (R12): one 1024-thread block/graph for k3; stage once, reg-accumulate.
// NOTE (R13): weights preconverted once; xp/G moved into k3; partials deleted.
// NOTE (R14): k4 fused into k3 tail via LDS union (cnt/T1T <-> xpL/Ap/h2/tt).
// xp/Ap never leave the block; tail is wave-local per cluster row (1 barrier).

typedef __attribute__((ext_vector_type(8))) _Float16 v8h;
typedef __attribute__((ext_vector_type(4))) float v4f;

// Inter-kernel intermediates as statics: no hipMalloc, graph-capture safe.
// Every element is rewritten each launch before being read.
__device__ float g_xagg[NTOT * 8];                  // x+agg, padded to 8
__device__ _Float16 g_W1bT[HD * HD];                // W1b^T [d][j] f16
__device__ _Float16 g_WpT[HD * HD];                 // Wp^T  [k][d] f16 (k>=50 = 0)
__device__ _Float16 g_ShT[(size_t)NG * KC * 256];   // S^T per graph [k][n], f16
__device__ _Float16 g_hT[(size_t)NG * HD * 256];    // h^T per graph [d][n], f16

__global__ void zero_ws(float* ws) {
    if (threadIdx.x < 4) ws[threadIdx.x] = 0.f;
}

// one-shot weight f16 preconversion (same work every launch; capture-safe)
__global__ void kw_conv(const float* __restrict__ W1b, const float* __restrict__ Wp) {
    const int tid = threadIdx.x;
    for (int i = tid; i < HD * HD; i += 1024) {
        int d = i >> 6, j = i & 63;
        g_W1bT[i] = (_Float16)W1b[j * HD + d];
    }
    for (int i = tid; i < HD * HD; i += 1024) {
        int k = i >> 6, d = i & 63;
        g_WpT[i] = (k < KC) ? (_Float16)Wp[d * KC + k] : (_Float16)0.f;
    }
}

// ws[0]=sumA2, ws[1]=sum S logS, ws[2]=trace(Ap)=sum(A.SSt), ws[3]=||G||^2
__global__ void finalize_k(const float* __restrict__ ws, float* __restrict__ out) {
    if (threadIdx.x == 0) {
        float num = ws[0] - 2.f * ws[2] + ws[3];
        float link = sqrtf(fmaxf(num, 0.f)) / 67108864.0f;   // / (B*n*n)
        float ent  = -ws[1] / 262144.0f;                     // / N
        out[2048] = link + ent;
    }
}

__device__ __forceinline__ float blockReduceN(float v, float* red, int nw) {
    __syncthreads();
    #pragma unroll
    for (int o = 32; o > 0; o >>= 1) v += __shfl_down(v, o);
    if ((threadIdx.x & 63) == 0) red[threadIdx.x >> 6] = v;
    __syncthreads();
    float r = 0.f;
    if (threadIdx.x == 0) {
        for (int i = 0; i < nw; ++i) r += red[i];
    }
    return r;
}

// ---- K1a: di counting sort + gather GIN aggregation -------------------------
// LDS ~25 KB -> 3 blocks/CU
__launch_bounds__(512, 3)
__global__ void k1a_sort(const int* __restrict__ esrc, const int* __restrict__ edst,
                         const float* __restrict__ x)
{
    __shared__ unsigned short cells[EPG];       // 8 KB
    __shared__ unsigned char ssi[EPG];          // 4 KB  (di-sorted si)
    __shared__ float xt8[NP * 8];               // 8 KB  (x, stride 8, pad 0)
    __shared__ unsigned int hist_di[256], cur_di[256];
    __shared__ unsigned int roff_di[NP + 1];

    const int g = blockIdx.x, tid = threadIdx.x;
    const int lane = tid & 63, wid = tid >> 6;

    if (tid < 256) hist_di[tid] = 0u;
    __syncthreads();

    for (int e = tid; e < EPG; e += 512) {
        int s = esrc[g * EPG + e] & (NP - 1);
        int d = edst[g * EPG + e] & (NP - 1);
        cells[e] = (unsigned short)((s << 8) | d);
        atomicAdd(&hist_di[d], 1u);
    }
    for (int i = tid; i < NP * 8; i += 512) {
        int n = i >> 3, f = i & 7;
        xt8[i] = (f < FIN) ? x[g * NP * FIN + n * FIN + f] : 0.f;
    }
    __syncthreads();

    // exclusive scan (wave 0)
    if (wid == 0) {
        unsigned carry = 0;
        for (int c = 0; c < 4; ++c) {
            unsigned v = hist_di[c * 64 + lane];
            unsigned s = v;
            #pragma unroll
            for (int o = 1; o < 64; o <<= 1) {
                unsigned t = __shfl_up(s, o);
                if (lane >= o) s += t;
            }
            unsigned excl = s - v + carry;
            roff_di[c * 64 + lane] = excl;
            cur_di[c * 64 + lane] = excl;
            carry += __shfl(s, 63);
        }
        if (lane == 0) roff_di[NP] = EPG;
    }
    __syncthreads();

    for (int e = tid; e < EPG; e += 512) {
        int c = cells[e]; int si = c >> 8, di = c & 255;
        unsigned p2 = atomicAdd(&cur_di[di], 1u);
        ssi[p2] = (unsigned char)si;
    }
    __syncthreads();

    // gather agg: 8 lanes per node (f = lane&7), write x+agg
    {
        const int gidx = tid >> 3, f = tid & 7;
        for (int n = gidx; n < NP; n += 64) {
            int beg = roff_di[n], end = roff_di[n + 1];
            float a = xt8[n * 8 + f];
            for (int e = beg; e < end; ++e)
                a += xt8[ssi[e] * 8 + f];
            g_xagg[g * NP * 8 + n * 8 + f] = a;
        }
    }
}

// ---- K2: MFMA f16 — MLP1, h-GEMM, P-GEMM, softmax; emits S^T, h^T -----------
__launch_bounds__(512, 2)
__global__ void k2_mlp(const float* __restrict__ W1a, const float* __restrict__ b1a,
                       const float* __restrict__ b1b, const float* __restrict__ bp,
                       float* __restrict__ ws)
{
    __shared__ __align__(16) float xt[CHK * 8];          // 2 KB
    __shared__ __align__(16) _Float16 t1b[CHK * FST];    // 9.2 KB  t1   [n][j]
    __shared__ __align__(16) _Float16 W1bT[HD * FST];    // 9.2 KB  W1b^T[d][j]
    __shared__ __align__(16) _Float16 WpT[HD * FST];     // 9.2 KB  Wp^T [k][d]
    __shared__ __align__(16) _Float16 hN[CHK * FST];     // 9.2 KB  h    [n][d]
    __shared__ __align__(16) _Float16 hT[HD * FST];      // 9.2 KB  h^T  [d][n]
    __shared__ __align__(16) _Float16 StT[HD * FST];     // 9.2 KB  S^T  [k][n]
    __shared__ __align__(16) float Pf[CHK * 66];         // 16.9 KB P    [n][k]
    __shared__ float red[8];

    const int b = blockIdx.x, rbase = b * CHK, tid = threadIdx.x;
    const int g = b >> 2, ch = b & 3;
    const int lane = tid & 63, wid = tid >> 6;
    const int l15 = lane & 15, quad = lane >> 4;
    const int fko = quad * 8;

    xt[tid] = g_xagg[rbase * 8 + tid];
    // stage preconverted weights (u32 vector copies, no cvt)
    for (int i = tid; i < HD * 32; i += 512) {
        int r = i >> 5, o = i & 31;
        ((unsigned int*)W1bT)[r * 36 + o] = ((const unsigned int*)g_W1bT)[r * 32 + o];
        ((unsigned int*)WpT)[r * 36 + o]  = ((const unsigned int*)g_WpT)[r * 32 + o];
    }
    __syncthreads();

    // t1 = relu((x+agg) @ W1a + b1a)
    {
        float w1r[FIN];
        #pragma unroll
        for (int f = 0; f < FIN; ++f) w1r[f] = W1a[f * HD + lane];
        float br = b1a[lane];
        for (int n = wid; n < CHK; n += 8) {
            float a = br;
            #pragma unroll
            for (int f = 0; f < FIN; ++f) a += xt[n * 8 + f] * w1r[f];
            t1b[n * FST + lane] = (_Float16)fmaxf(a, 0.f);
        }
    }
    __syncthreads();

    // h = t1 @ W1b + b1b
    for (int t = wid * 2; t < wid * 2 + 2; ++t) {
        int mt = (t >> 2) << 4, nt = (t & 3) << 4;
        v4f acc = {0.f, 0.f, 0.f, 0.f};
        #pragma unroll
        for (int ks = 0; ks < 2; ++ks) {
            v8h af = *(const v8h*)&t1b[(mt + l15) * FST + ks * 32 + fko];
            v8h bf = *(const v8h*)&W1bT[(nt + l15) * FST + ks * 32 + fko];
            acc = __builtin_amdgcn_mfma_f32_16x16x32_f16(af, bf, acc, 0, 0, 0);
        }
        int d = nt + l15;
        float bv = b1b[d];
        #pragma unroll
        for (int r = 0; r < 4; ++r) {
            int m = mt + quad * 4 + r;
            _Float16 hv = (_Float16)(acc[r] + bv);
            hN[m * FST + d] = hv;
            hT[d * FST + m] = hv;
        }
    }
    __syncthreads();

    // persist h^T chunk (coalesced u32)
    for (int i = tid; i < HD * 32; i += 512) {
        int d = i >> 5, o = i & 31;
        unsigned w = *(const unsigned int*)&hT[d * FST + 2 * o];
        ((unsigned int*)g_hT)[((size_t)g * HD + d) * 128 + ch * 32 + o] = w;
    }

    // P = h @ Wp + bp
    for (int t = wid * 2; t < wid * 2 + 2; ++t) {
        int mt = (t >> 2) << 4, nt = (t & 3) << 4;
        v4f acc = {0.f, 0.f, 0.f, 0.f};
        #pragma unroll
        for (int ks = 0; ks < 2; ++ks) {
            v8h af = *(const v8h*)&hN[(mt + l15) * FST + ks * 32 + fko];
            v8h bf = *(const v8h*)&WpT[(nt + l15) * FST + ks * 32 + fko];
            acc = __builtin_amdgcn_mfma_f32_16x16x32_f16(af, bf, acc, 0, 0, 0);
        }
        int kcol = nt + l15;
        if (kcol < KC) {
            float bv = bp[kcol];
            #pragma unroll
            for (int r = 0; r < 4; ++r)
                Pf[(mt + quad * 4 + r) * 66 + kcol] = acc[r] + bv;
        }
    }
    __syncthreads();

    // softmax -> StT f16 [k][n], entropy partial
    float entL = 0.f;
    for (int n = wid; n < CHK; n += 8) {
        float a = (lane < KC) ? Pf[n * 66 + lane] : -INFINITY;
        float m = a;
        #pragma unroll
        for (int o = 32; o > 0; o >>= 1) m = fmaxf(m, __shfl_xor(m, o));
        float e = expf(a - m);
        float ss = e;
        #pragma unroll
        for (int o = 32; o > 0; o >>= 1) ss += __shfl_xor(ss, o);
        float s = e / ss;
        if (lane < KC) {
            StT[lane * FST + n] = (_Float16)s;
            entL += s * logf(s + 1e-15f);
        }
    }
    __syncthreads();

    // persist S^T chunk (coalesced u32)
    for (int i = tid; i < KC * 32; i += 512) {
        int k = i >> 5, o = i & 31;
        unsigned w = *(const unsigned int*)&StT[k * FST + 2 * o];
        ((unsigned int*)g_ShT)[((size_t)g * KC + k) * 128 + ch * 32 + o] = w;
    }

    float r = blockReduceN(entL, red, 8);
    if (tid == 0) atomicAdd(&ws[1], r);
}

// ---- K3_fused: dense-A slabs + MFMA AS/Ap/xp/G + fused dense-GIN head -------
// One 1024-thread block per graph. Slab phase uses u.a (cnt/T1T); tail phase
// reuses the same LDS as u.b (xpL/Ap/h2/tt). LDS ~124 KB -> 1 block/CU.
__launch_bounds__(1024, 1)
__global__ void k3_fused(const int* __restrict__ esrc, const int* __restrict__ edst,
                         const float* __restrict__ W2a, const float* __restrict__ b2a,
                         const float* __restrict__ W2b, const float* __restrict__ b2b,
                         const float* __restrict__ Wl,  const float* __restrict__ bl,
                         float* __restrict__ out, float* __restrict__ ws)
{
    __shared__ __align__(16) union {
        struct {
            unsigned int cnt[64 * ASTW];         // 33 KB; becomes f16 A[64][264]
            _Float16 T1T[64 * 72];               // 9 KB   AS^T [c][nrow]
        } a;
        struct {
            float xpL[KC * HD];                  // 12.8 KB  xp [k][d]
            float Ap[KC * KC];                   // 10 KB
            float h2[KC * HD];                   // 12.8 KB
            float tt[KC * HD];                   // 12.8 KB
        } b;
    } u;
    __shared__ __align__(16) _Float16 ST[64 * ASTR]; // 33 KB  S^T [k][n] padded
    __shared__ __align__(16) _Float16 HT[64 * ASTR]; // 33 KB  h^T [d][n] padded
    __shared__ unsigned short cells[EPG];            // 8 KB
    __shared__ float red[16];

    const int g = blockIdx.x, tid = threadIdx.x;
    const int lane = tid & 63, wid = tid >> 6;       // wid 0..15
    const int l15 = lane & 15, quad = lane >> 4, fko = quad * 8;
    const int mt = (wid >> 2) << 4, nt = (wid & 3) << 4;   // this wave's tile

    // stage S^T and h^T once (zero S^T rows k>=50; zero col pads on both)
    for (int i = tid; i < 64 * 128; i += 1024) {
        int k = i >> 7, o = i & 127;
        ((unsigned int*)ST)[k * ASTW + o] = (k < KC)
            ? ((const unsigned int*)g_ShT)[((size_t)g * KC + k) * 128 + o] : 0u;
        ((unsigned int*)HT)[k * ASTW + o] =
            ((const unsigned int*)g_hT)[((size_t)g * HD + k) * 128 + o];
    }
    for (int i = tid; i < 64 * 4; i += 1024) {
        ((unsigned int*)ST)[(i >> 2) * ASTW + 128 + (i & 3)] = 0u;
        ((unsigned int*)HT)[(i >> 2) * ASTW + 128 + (i & 3)] = 0u;
    }
    // stage edges once
    for (int e = tid; e < EPG; e += 1024) {
        int s = esrc[g * EPG + e] & (NP - 1);
        int d = edst[g * EPG + e] & (NP - 1);
        cells[e] = (unsigned short)((s << 8) | d);
    }
    __syncthreads();

    float sumA2 = 0.f;
    v4f ap  = {0.f, 0.f, 0.f, 0.f};                  // Ap tile
    v4f axp = {0.f, 0.f, 0.f, 0.f};                  // xp tile
    v4f ag  = {0.f, 0.f, 0.f, 0.f};                  // G tile

    for (int ch = 0; ch < 4; ++ch) {
        for (int i = tid; i < 64 * ASTW; i += 1024) u.a.cnt[i] = 0u;
        __syncthreads();

        // count this slab's cells (rows s in [ch*64, ch*64+64))
        int rlo = ch << 6;
        for (int e = tid; e < EPG; e += 1024) {
            int c = cells[e];
            int sr = (c >> 8) - rlo;
            if ((unsigned)sr < 64u) {
                int d = c & 255;
                atomicAdd(&u.a.cnt[sr * ASTW + (d >> 1)], (d & 1) ? 0x10000u : 1u);
            }
        }
        __syncthreads();

        // sum(A^2) partial + in-place convert counts -> f16 (pads stay 0)
        for (int i = tid; i < 64 * ASTW; i += 1024) {
            unsigned v = u.a.cnt[i];
            float m0 = (float)(v & 0xffffu), m1 = (float)(v >> 16);
            sumA2 += m0 * m0 + m1 * m1;
            union { unsigned uu; _Float16 h[2]; } cv;
            cv.h[0] = (_Float16)m0; cv.h[1] = (_Float16)m1;
            u.a.cnt[i] = cv.uu;
        }
        __syncthreads();

        const _Float16* Af = (const _Float16*)u.a.cnt;   // A slab [64][264]

        // AS_slab = A_slab @ S : 16 tiles, 1 per wave
        {
            v4f acc = {0.f, 0.f, 0.f, 0.f};
            #pragma unroll
            for (int ks = 0; ks < 8; ++ks) {
                v8h af = *(const v8h*)&Af[(mt + l15) * ASTR + ks * 32 + fko];
                v8h bf = *(const v8h*)&ST[(nt + l15) * ASTR + ks * 32 + fko];
                acc = __builtin_amdgcn_mfma_f32_16x16x32_f16(af, bf, acc, 0, 0, 0);
            }
            int c = nt + l15;
            #pragma unroll
            for (int r = 0; r < 4; ++r)
                u.a.T1T[c * 72 + mt + quad * 4 + r] = (_Float16)acc[r];
        }
        __syncthreads();

        // Ap += S_slab^T @ AS_slab; xp += S_slab^T @ h_slab; G += S^T S (slab)
        #pragma unroll
        for (int ks = 0; ks < 2; ++ks) {
            int ko = (ch << 6) + ks * 32 + fko;
            v8h af = *(const v8h*)&ST[(mt + l15) * ASTR + ko];
            v8h bt = *(const v8h*)&u.a.T1T[(nt + l15) * 72 + ks * 32 + fko];
            v8h bh = *(const v8h*)&HT[(nt + l15) * ASTR + ko];
            v8h bs = *(const v8h*)&ST[(nt + l15) * ASTR + ko];
            ap  = __builtin_amdgcn_mfma_f32_16x16x32_f16(af, bt, ap, 0, 0, 0);
            axp = __builtin_amdgcn_mfma_f32_16x16x32_f16(af, bh, axp, 0, 0, 0);
            ag  = __builtin_amdgcn_mfma_f32_16x16x32_f16(af, bs, ag, 0, 0, 0);
        }
        __syncthreads();    // u.a reused next slab
    }

    // scalars from tiles; flip union to tail mode (all u.a reads complete)
    float tr = 0.f, g2 = 0.f;
    {
        int c = nt + l15;
        #pragma unroll
        for (int r = 0; r < 4; ++r) {
            int k = mt + quad * 4 + r;
            if (k < KC) {
                u.b.xpL[k * HD + c] = axp[r];
                if (c < KC) {
                    u.b.Ap[k * KC + c] = ap[r];
                    if (k == c) tr += ap[r];
                    g2 += ag[r] * ag[r];
                }
            }
        }
    }

    float rA = blockReduceN(sumA2, red, 16);   // internal barriers also fence u.b
    float rT = blockReduceN(tr, red, 16);
    float rG = blockReduceN(g2, red, 16);
    if (tid == 0) {
        atomicAdd(&ws[0], rA);
        atomicAdd(&ws[2], rT);
        atomicAdd(&ws[3], rG);
    }
    __syncthreads();   // xpL/Ap fully visible

    // ---- fused k4 tail: wave-local per cluster row k (no more barriers) ----
    // h2[k][d] = xp[k][d] + sum_l Ap[k][l] * xp[l][d]
    for (int k = wid; k < KC; k += 16) {
        float a = u.b.xpL[k * HD + lane];
        #pragma unroll
        for (int l = 0; l < KC; ++l)
            a += u.b.Ap[k * KC + l] * u.b.xpL[l * HD + lane];
        u.b.h2[k * HD + lane] = a;
    }

    // t = relu(h2 @ W2a + b2a)   (same wave owns the same k rows)
    {
        float wr[HD];
        #pragma unroll
        for (int d = 0; d < HD; ++d) wr[d] = W2a[d * HD + lane];
        float br = b2a[lane];
        for (int k = wid; k < KC; k += 16) {
            float a0 = br, a1 = 0.f, a2 = 0.f, a3 = 0.f;
            const float4* h4 = (const float4*)&u.b.h2[k * HD];
            #pragma unroll
            for (int i = 0; i < 16; ++i) {
                float4 v = h4[i];
                a0 += v.x * wr[4*i]; a1 += v.y * wr[4*i+1];
                a2 += v.z * wr[4*i+2]; a3 += v.w * wr[4*i+3];
            }
            u.b.tt[k * HD + lane] = fmaxf((a0 + a1) + (a2 + a3), 0.f);
        }
    }

    // h3 = t @ W2b + b2b; fold mean over k and Wl into logits partials
    float l0 = 0.f, l1 = 0.f;
    {
        float wr[HD];
        #pragma unroll
        for (int j = 0; j < HD; ++j) wr[j] = W2b[j * HD + lane];
        float br = b2b[lane];
        float wl0 = Wl[lane * 2], wl1 = Wl[lane * 2 + 1];
        for (int k = wid; k < KC; k += 16) {
            float a0 = br, a1 = 0.f, a2 = 0.f, a3 = 0.f;
            const float4* t4 = (const float4*)&u.b.tt[k * HD];
            #pragma unroll
            for (int i = 0; i < 16; ++i) {
                float4 v = t4[i];
                a0 += v.x * wr[4*i]; a1 += v.y * wr[4*i+1];
                a2 += v.z * wr[4*i+2]; a3 += v.w * wr[4*i+3];
            }
            float a = (a0 + a1) + (a2 + a3);
            l0 += a * wl0; l1 += a * wl1;
        }
    }

    float rl0 = blockReduceN(l0, red, 16);
    float rl1 = blockReduceN(l1, red, 16);
    if (tid == 0) {
        float g0 = bl[0] + rl0 * (1.f / KC);
        float g1 = bl[1] + rl1 * (1.f / KC);
        float mm = fmaxf(g0, g1);
        float lse = mm + logf(expf(g0 - mm) + expf(g1 - mm));
        out[2 * g]     = g0 - lse;
        out[2 * g + 1] = g1 - lse;
    }
}

extern "C" void kernel_launch(void* const* d_in, const int* in_sizes, int n_in,
                              void* d_out, int out_size, void* d_ws, size_t ws_size,
                              hipStream_t stream) {
    const float* x    = (const float*)d_in[0];
    const float* W1a  = (const float*)d_in[1];
    const float* b1a  = (const float*)d_in[2];
    const float* W1b  = (const float*)d_in[3];
    const float* b1b  = (const float*)d_in[4];
    const float* Wp   = (const float*)d_in[5];
    const float* bp   = (const float*)d_in[6];
    const float* W2a  = (const float*)d_in[7];
    const float* b2a  = (const float*)d_in[8];
    const float* W2b  = (const float*)d_in[9];
    const float* b2b  = (const float*)d_in[10];
    const float* Wl   = (const float*)d_in[11];
    const float* bl   = (const float*)d_in[12];
    const int*   eidx = (const int*)d_in[13];   // [2, E] int32
    float* out = (float*)d_out;
    float* ws  = (float*)d_ws;

    zero_ws<<<1, 64, 0, stream>>>(ws);
    kw_conv<<<1, 1024, 0, stream>>>(W1b, Wp);
    k1a_sort<<<NG, 512, 0, stream>>>(eidx, eidx + ETOT, x);
    k2_mlp<<<NG * NCH, 512, 0, stream>>>(W1a, b1a, b1b, bp, ws);
    k3_fused<<<NG, 1024, 0, stream>>>(eidx, eidx + ETOT,
                                      W2a, b2a, W2b, b2b, Wl, bl, out, ws);
    finalize_k<<<1, 64, 0, stream>>>(ws, out);
}

// Round 16
// 321.362 us; speedup vs baseline: 1.6309x; 1.0571x over previous
//
#include <hip/hip_runtime.h>
#include <math.h>

// Problem constants (from reference)
#define NG   1024        // graphs
#define NP   256         // nodes per graph
#define EPG  4096        // edges per graph
#define ETOT 4194304     // total edges
#define NTOT (NG * NP)   // 262144 nodes
#define FIN  7
#define HD   64
#define KC   50
#define CHK  64          // rows per K2 chunk
#define NCH  4           // chunks per graph
#define FST  72          // f16 LDS row stride in k2 (144 B rows, 16B-aligned)
#define ASTR 264         // k3 f16 row stride: 132 words = 4 mod 32 (2-way free)
#define ASTW 132         // ASTR in u32 words
#define TSC  0.00390625f // tail scale 1/256 (exact): keeps h2*s, t*s in f16 range
#define TSCI 256.0f      // inverse

// NOTE (R2): __launch_bounds__ 2nd arg acts as CUDA-style min BLOCKS/CU.
// NOTE (R3): LDS atomic scatter -> counting-sort gather.
// NOTE (R4): persistent per-lane arrays spill at the VGPR cap -> wave-row regs.
// NOTE (R5): GEMV-style phases are latency-bound -> f16 MFMA GEMMs.
// NOTE (R8): f16 scalar gathers add a cvt per element -> regressed.
// NOTE (R10/R11): dense-A slabs + MFMA; stride 264 kills 16-way conflicts.
// NOTE (R12): one 1024-thread block/graph for k3; stage once, reg-accumulate.
// NOTE (R13): weights preconverted once; xp/G moved into k3; partials deleted.
// NOTE (R14): k4 fused into k3 tail (VALU: 12.6 us/block).
// NOTE (R15): MFMA tail NaN'd: Ap@xp reaches O(1e5) > f16 max; h2f stored inf,
// inf-inf=NaN in log_softmax. R16: scale h2/t by 1/256 through the relu
// (positively homogeneous, exact pow2), unscale in the fp32 logit fold.

typedef __attribute__((ext_vector_type(8))) _Float16 v8h;
typedef __attribute__((ext_vector_type(4))) float v4f;

// Inter-kernel intermediates as statics: no hipMalloc, graph-capture safe.
// Every element is rewritten each launch before being read.
__device__ float g_xagg[NTOT * 8];                          // x+agg, padded to 8
__device__ __align__(16) _Float16 g_W1bT[HD * HD];          // W1b^T [d][j] f16
__device__ __align__(16) _Float16 g_WpT[HD * HD];           // Wp^T  [k][d] f16
__device__ __align__(16) _Float16 g_W2aT[HD * HD];          // W2a^T [d2][d] f16
__device__ __align__(16) _Float16 g_W2bT[HD * HD];          // W2b^T [j][d2] f16
__device__ __align__(16) _Float16 g_ShT[(size_t)NG * KC * 256]; // S^T [k][n] f16
__device__ __align__(16) _Float16 g_hT[(size_t)NG * HD * 256];  // h^T [d][n] f16

__global__ void zero_ws(float* ws) {
    if (threadIdx.x < 4) ws[threadIdx.x] = 0.f;
}

// one-shot weight f16 preconversion (same work every launch; capture-safe)
__global__ void kw_conv(const float* __restrict__ W1b, const float* __restrict__ Wp,
                        const float* __restrict__ W2a, const float* __restrict__ W2b) {
    const int tid = threadIdx.x;
    for (int i = tid; i < HD * HD; i += 1024) {
        int d = i >> 6, j = i & 63;
        g_W1bT[i] = (_Float16)W1b[j * HD + d];      // [d][j]
        g_W2aT[i] = (_Float16)W2a[j * HD + d];      // [d2][d]
        g_W2bT[i] = (_Float16)W2b[j * HD + d];      // [j][d2]
    }
    for (int i = tid; i < HD * HD; i += 1024) {
        int k = i >> 6, d = i & 63;
        g_WpT[i] = (k < KC) ? (_Float16)Wp[d * KC + k] : (_Float16)0.f;
    }
}

// ws[0]=sumA2, ws[1]=sum S logS, ws[2]=trace(Ap)=sum(A.SSt), ws[3]=||G||^2
__global__ void finalize_k(const float* __restrict__ ws, float* __restrict__ out) {
    if (threadIdx.x == 0) {
        float num = ws[0] - 2.f * ws[2] + ws[3];
        float link = sqrtf(fmaxf(num, 0.f)) / 67108864.0f;   // / (B*n*n)
        float ent  = -ws[1] / 262144.0f;                     // / N
        out[2048] = link + ent;
    }
}

__device__ __forceinline__ float blockReduceN(float v, float* red, int nw) {
    __syncthreads();
    #pragma unroll
    for (int o = 32; o > 0; o >>= 1) v += __shfl_down(v, o);
    if ((threadIdx.x & 63) == 0) red[threadIdx.x >> 6] = v;
    __syncthreads();
    float r = 0.f;
    if (threadIdx.x == 0) {
        for (int i = 0; i < nw; ++i) r += red[i];
    }
    return r;
}

// ---- K1a: di counting sort + gather GIN aggregation -------------------------
// LDS ~25 KB -> 3 blocks/CU
__launch_bounds__(512, 3)
__global__ void k1a_sort(const int* __restrict__ esrc, const int* __restrict__ edst,
                         const float* __restrict__ x)
{
    __shared__ unsigned short cells[EPG];       // 8 KB
    __shared__ unsigned char ssi[EPG];          // 4 KB  (di-sorted si)
    __shared__ float xt8[NP * 8];               // 8 KB  (x, stride 8, pad 0)
    __shared__ unsigned int hist_di[256], cur_di[256];
    __shared__ unsigned int roff_di[NP + 1];

    const int g = blockIdx.x, tid = threadIdx.x;
    const int lane = tid & 63, wid = tid >> 6;

    if (tid < 256) hist_di[tid] = 0u;
    __syncthreads();

    for (int e = tid; e < EPG; e += 512) {
        int s = esrc[g * EPG + e] & (NP - 1);
        int d = edst[g * EPG + e] & (NP - 1);
        cells[e] = (unsigned short)((s << 8) | d);
        atomicAdd(&hist_di[d], 1u);
    }
    for (int i = tid; i < NP * 8; i += 512) {
        int n = i >> 3, f = i & 7;
        xt8[i] = (f < FIN) ? x[g * NP * FIN + n * FIN + f] : 0.f;
    }
    __syncthreads();

    // exclusive scan (wave 0)
    if (wid == 0) {
        unsigned carry = 0;
        for (int c = 0; c < 4; ++c) {
            unsigned v = hist_di[c * 64 + lane];
            unsigned s = v;
            #pragma unroll
            for (int o = 1; o < 64; o <<= 1) {
                unsigned t = __shfl_up(s, o);
                if (lane >= o) s += t;
            }
            unsigned excl = s - v + carry;
            roff_di[c * 64 + lane] = excl;
            cur_di[c * 64 + lane] = excl;
            carry += __shfl(s, 63);
        }
        if (lane == 0) roff_di[NP] = EPG;
    }
    __syncthreads();

    for (int e = tid; e < EPG; e += 512) {
        int c = cells[e]; int si = c >> 8, di = c & 255;
        unsigned p2 = atomicAdd(&cur_di[di], 1u);
        ssi[p2] = (unsigned char)si;
    }
    __syncthreads();

    // gather agg: 8 lanes per node (f = lane&7), write x+agg
    {
        const int gidx = tid >> 3, f = tid & 7;
        for (int n = gidx; n < NP; n += 64) {
            int beg = roff_di[n], end = roff_di[n + 1];
            float a = xt8[n * 8 + f];
            for (int e = beg; e < end; ++e)
                a += xt8[ssi[e] * 8 + f];
            g_xagg[g * NP * 8 + n * 8 + f] = a;
        }
    }
}

// ---- K2: MFMA f16 — MLP1, h-GEMM, P-GEMM, softmax; emits S^T, h^T -----------
__launch_bounds__(512, 2)
__global__ void k2_mlp(const float* __restrict__ W1a, const float* __restrict__ b1a,
                       const float* __restrict__ b1b, const float* __restrict__ bp,
                       float* __restrict__ ws)
{
    __shared__ __align__(16) float xt[CHK * 8];          // 2 KB
    __shared__ __align__(16) _Float16 t1b[CHK * FST];    // 9.2 KB  t1   [n][j]
    __shared__ __align__(16) _Float16 W1bT[HD * FST];    // 9.2 KB  W1b^T[d][j]
    __shared__ __align__(16) _Float16 WpT[HD * FST];     // 9.2 KB  Wp^T [k][d]
    __shared__ __align__(16) _Float16 hN[CHK * FST];     // 9.2 KB  h    [n][d]
    __shared__ __align__(16) _Float16 hT[HD * FST];      // 9.2 KB  h^T  [d][n]
    __shared__ __align__(16) _Float16 StT[HD * FST];     // 9.2 KB  S^T  [k][n]
    __shared__ __align__(16) float Pf[CHK * 66];         // 16.9 KB P    [n][k]
    __shared__ float red[8];

    const int b = blockIdx.x, rbase = b * CHK, tid = threadIdx.x;
    const int g = b >> 2, ch = b & 3;
    const int lane = tid & 63, wid = tid >> 6;
    const int l15 = lane & 15, quad = lane >> 4;
    const int fko = quad * 8;

    xt[tid] = g_xagg[rbase * 8 + tid];
    // stage preconverted weights (u32 vector copies, no cvt)
    for (int i = tid; i < HD * 32; i += 512) {
        int r = i >> 5, o = i & 31;
        ((unsigned int*)W1bT)[r * 36 + o] = ((const unsigned int*)g_W1bT)[r * 32 + o];
        ((unsigned int*)WpT)[r * 36 + o]  = ((const unsigned int*)g_WpT)[r * 32 + o];
    }
    __syncthreads();

    // t1 = relu((x+agg) @ W1a + b1a)
    {
        float w1r[FIN];
        #pragma unroll
        for (int f = 0; f < FIN; ++f) w1r[f] = W1a[f * HD + lane];
        float br = b1a[lane];
        for (int n = wid; n < CHK; n += 8) {
            float a = br;
            #pragma unroll
            for (int f = 0; f < FIN; ++f) a += xt[n * 8 + f] * w1r[f];
            t1b[n * FST + lane] = (_Float16)fmaxf(a, 0.f);
        }
    }
    __syncthreads();

    // h = t1 @ W1b + b1b
    for (int t = wid * 2; t < wid * 2 + 2; ++t) {
        int mt = (t >> 2) << 4, nt = (t & 3) << 4;
        v4f acc = {0.f, 0.f, 0.f, 0.f};
        #pragma unroll
        for (int ks = 0; ks < 2; ++ks) {
            v8h af = *(const v8h*)&t1b[(mt + l15) * FST + ks * 32 + fko];
            v8h bf = *(const v8h*)&W1bT[(nt + l15) * FST + ks * 32 + fko];
            acc = __builtin_amdgcn_mfma_f32_16x16x32_f16(af, bf, acc, 0, 0, 0);
        }
        int d = nt + l15;
        float bv = b1b[d];
        #pragma unroll
        for (int r = 0; r < 4; ++r) {
            int m = mt + quad * 4 + r;
            _Float16 hv = (_Float16)(acc[r] + bv);
            hN[m * FST + d] = hv;
            hT[d * FST + m] = hv;
        }
    }
    __syncthreads();

    // persist h^T chunk (coalesced u32)
    for (int i = tid; i < HD * 32; i += 512) {
        int d = i >> 5, o = i & 31;
        unsigned w = *(const unsigned int*)&hT[d * FST + 2 * o];
        ((unsigned int*)g_hT)[((size_t)g * HD + d) * 128 + ch * 32 + o] = w;
    }

    // P = h @ Wp + bp
    for (int t = wid * 2; t < wid * 2 + 2; ++t) {
        int mt = (t >> 2) << 4, nt = (t & 3) << 4;
        v4f acc = {0.f, 0.f, 0.f, 0.f};
        #pragma unroll
        for (int ks = 0; ks < 2; ++ks) {
            v8h af = *(const v8h*)&hN[(mt + l15) * FST + ks * 32 + fko];
            v8h bf = *(const v8h*)&WpT[(nt + l15) * FST + ks * 32 + fko];
            acc = __builtin_amdgcn_mfma_f32_16x16x32_f16(af, bf, acc, 0, 0, 0);
        }
        int kcol = nt + l15;
        if (kcol < KC) {
            float bv = bp[kcol];
            #pragma unroll
            for (int r = 0; r < 4; ++r)
                Pf[(mt + quad * 4 + r) * 66 + kcol] = acc[r] + bv;
        }
    }
    __syncthreads();

    // softmax -> StT f16 [k][n], entropy partial
    float entL = 0.f;
    for (int n = wid; n < CHK; n += 8) {
        float a = (lane < KC) ? Pf[n * 66 + lane] : -INFINITY;
        float m = a;
        #pragma unroll
        for (int o = 32; o > 0; o >>= 1) m = fmaxf(m, __shfl_xor(m, o));
        float e = expf(a - m);
        float ss = e;
        #pragma unroll
        for (int o = 32; o > 0; o >>= 1) ss += __shfl_xor(ss, o);
        float s = e / ss;
        if (lane < KC) {
            StT[lane * FST + n] = (_Float16)s;
            entL += s * logf(s + 1e-15f);
        }
    }
    __syncthreads();

    // persist S^T chunk (coalesced u32)
    for (int i = tid; i < KC * 32; i += 512) {
        int k = i >> 5, o = i & 31;
        unsigned w = *(const unsigned int*)&StT[k * FST + 2 * o];
        ((unsigned int*)g_ShT)[((size_t)g * KC + k) * 128 + ch * 32 + o] = w;
    }

    float r = blockReduceN(entL, red, 8);
    if (tid == 0) atomicAdd(&ws[1], r);
}

// ---- K3_fused: dense-A slabs + MFMA AS/Ap/xp/G + MFMA dense-GIN head --------
// One 1024-thread block per graph. Slab phase: u.a (cnt/T1T); tail phase: u.b
// (Apf/xpT/h2f/tf, f16 stride 72). Tail intermediates scaled by 1/256 to stay
// in f16 range (relu is positively homogeneous; unscaled in fp32 logit fold).
__launch_bounds__(1024, 1)
__global__ void k3_fused(const int* __restrict__ esrc, const int* __restrict__ edst,
                         const float* __restrict__ b2a, const float* __restrict__ b2b,
                         const float* __restrict__ Wl,  const float* __restrict__ bl,
                         float* __restrict__ out, float* __restrict__ ws)
{
    __shared__ __align__(16) union {
        struct {
            unsigned int cnt[64 * ASTW];         // 33 KB; becomes f16 A[64][264]
            _Float16 T1T[64 * 72];               // 9 KB   AS^T [c][nrow]
        } a;
        struct {
            _Float16 Apf[64 * 72];               // 9.2 KB  Ap  [k][l] (pads 0)
            _Float16 xpT[64 * 72];               // 9.2 KB  xp^T[d][l]
            _Float16 h2f[64 * 72];               // 9.2 KB  h2*s [k][d]
            _Float16 tf[64 * 72];                // 9.2 KB  t*s  [k][d2]
        } b;
    } u;
    __shared__ __align__(16) _Float16 ST[64 * ASTR]; // 33 KB  S^T [k][n] padded
    __shared__ __align__(16) _Float16 HT[64 * ASTR]; // 33 KB  h^T [d][n] padded
    __shared__ unsigned short cells[EPG];            // 8 KB
    __shared__ float red[16];

    const int g = blockIdx.x, tid = threadIdx.x;
    const int lane = tid & 63, wid = tid >> 6;       // wid 0..15
    const int l15 = lane & 15, quad = lane >> 4, fko = quad * 8;
    const int mt = (wid >> 2) << 4, nt = (wid & 3) << 4;   // this wave's tile

    // stage S^T and h^T once (zero S^T rows k>=50; zero col pads on both)
    for (int i = tid; i < 64 * 128; i += 1024) {
        int k = i >> 7, o = i & 127;
        ((unsigned int*)ST)[k * ASTW + o] = (k < KC)
            ? ((const unsigned int*)g_ShT)[((size_t)g * KC + k) * 128 + o] : 0u;
        ((unsigned int*)HT)[k * ASTW + o] =
            ((const unsigned int*)g_hT)[((size_t)g * HD + k) * 128 + o];
    }
    for (int i = tid; i < 64 * 4; i += 1024) {
        ((unsigned int*)ST)[(i >> 2) * ASTW + 128 + (i & 3)] = 0u;
        ((unsigned int*)HT)[(i >> 2) * ASTW + 128 + (i & 3)] = 0u;
    }
    // stage edges once
    for (int e = tid; e < EPG; e += 1024) {
        int s = esrc[g * EPG + e] & (NP - 1);
        int d = edst[g * EPG + e] & (NP - 1);
        cells[e] = (unsigned short)((s << 8) | d);
    }
    __syncthreads();

    float sumA2 = 0.f;
    v4f ap  = {0.f, 0.f, 0.f, 0.f};                  // Ap tile
    v4f axp = {0.f, 0.f, 0.f, 0.f};                  // xp tile
    v4f ag  = {0.f, 0.f, 0.f, 0.f};                  // G tile

    for (int ch = 0; ch < 4; ++ch) {
        for (int i = tid; i < 64 * ASTW; i += 1024) u.a.cnt[i] = 0u;
        __syncthreads();

        // count this slab's cells (rows s in [ch*64, ch*64+64))
        int rlo = ch << 6;
        for (int e = tid; e < EPG; e += 1024) {
            int c = cells[e];
            int sr = (c >> 8) - rlo;
            if ((unsigned)sr < 64u) {
                int d = c & 255;
                atomicAdd(&u.a.cnt[sr * ASTW + (d >> 1)], (d & 1) ? 0x10000u : 1u);
            }
        }
        __syncthreads();

        // sum(A^2) partial + in-place convert counts -> f16 (pads stay 0)
        for (int i = tid; i < 64 * ASTW; i += 1024) {
            unsigned v = u.a.cnt[i];
            float m0 = (float)(v & 0xffffu), m1 = (float)(v >> 16);
            sumA2 += m0 * m0 + m1 * m1;
            union { unsigned uu; _Float16 h[2]; } cv;
            cv.h[0] = (_Float16)m0; cv.h[1] = (_Float16)m1;
            u.a.cnt[i] = cv.uu;
        }
        __syncthreads();

        const _Float16* Af = (const _Float16*)u.a.cnt;   // A slab [64][264]

        // AS_slab = A_slab @ S : 16 tiles, 1 per wave
        {
            v4f acc = {0.f, 0.f, 0.f, 0.f};
            #pragma unroll
            for (int ks = 0; ks < 8; ++ks) {
                v8h af = *(const v8h*)&Af[(mt + l15) * ASTR + ks * 32 + fko];
                v8h bf = *(const v8h*)&ST[(nt + l15) * ASTR + ks * 32 + fko];
                acc = __builtin_amdgcn_mfma_f32_16x16x32_f16(af, bf, acc, 0, 0, 0);
            }
            int c = nt + l15;
            #pragma unroll
            for (int r = 0; r < 4; ++r)
                u.a.T1T[c * 72 + mt + quad * 4 + r] = (_Float16)acc[r];
        }
        __syncthreads();

        // Ap += S_slab^T @ AS_slab; xp += S_slab^T @ h_slab; G += S^T S (slab)
        #pragma unroll
        for (int ks = 0; ks < 2; ++ks) {
            int ko = (ch << 6) + ks * 32 + fko;
            v8h af = *(const v8h*)&ST[(mt + l15) * ASTR + ko];
            v8h bt = *(const v8h*)&u.a.T1T[(nt + l15) * 72 + ks * 32 + fko];
            v8h bh = *(const v8h*)&HT[(nt + l15) * ASTR + ko];
            v8h bs = *(const v8h*)&ST[(nt + l15) * ASTR + ko];
            ap  = __builtin_amdgcn_mfma_f32_16x16x32_f16(af, bt, ap, 0, 0, 0);
            axp = __builtin_amdgcn_mfma_f32_16x16x32_f16(af, bh, axp, 0, 0, 0);
            ag  = __builtin_amdgcn_mfma_f32_16x16x32_f16(af, bs, ag, 0, 0, 0);
        }
        __syncthreads();    // u.a reused next slab
    }

    // scalars from tiles; write f16 Ap / xp^T (tiles are zero beyond KC by
    // construction: S rows >=50 are zero -> ap/axp rows&cols >=50 are zero)
    float tr = 0.f, g2 = 0.f;
    {
        int c = nt + l15;
        #pragma unroll
        for (int r = 0; r < 4; ++r) {
            int k = mt + quad * 4 + r;
            u.b.Apf[k * 72 + c] = (_Float16)ap[r];
            u.b.xpT[c * 72 + k] = (_Float16)axp[r];
            if (k < KC && c < KC) {
                if (k == c) tr += ap[r];
                g2 += ag[r] * ag[r];
            }
        }
    }

    float rA = blockReduceN(sumA2, red, 16);   // internal barriers fence u.b
    float rT = blockReduceN(tr, red, 16);
    float rG = blockReduceN(g2, red, 16);
    if (tid == 0) {
        atomicAdd(&ws[0], rA);
        atomicAdd(&ws[2], rT);
        atomicAdd(&ws[3], rG);
    }
    __syncthreads();

    // ---- MFMA tail: h2 = xp + Ap @ xp (fp32 acc init = live axp tile);
    //      store h2*TSC in f16 (overflow-proof) ----
    {
        v4f hacc = axp;
        #pragma unroll
        for (int ks = 0; ks < 2; ++ks) {
            v8h af = *(const v8h*)&u.b.Apf[(mt + l15) * 72 + ks * 32 + fko];
            v8h bf = *(const v8h*)&u.b.xpT[(nt + l15) * 72 + ks * 32 + fko];
            hacc = __builtin_amdgcn_mfma_f32_16x16x32_f16(af, bf, hacc, 0, 0, 0);
        }
        int d = nt + l15;
        #pragma unroll
        for (int r = 0; r < 4; ++r)
            u.b.h2f[(mt + quad * 4 + r) * 72 + d] = (_Float16)(hacc[r] * TSC);
    }
    __syncthreads();

    // t*s = relu(h2s @ W2a + s*b2a)   (B-frags from global preconverted f16)
    {
        float bv = b2a[nt + l15] * TSC;
        v4f tacc = {bv, bv, bv, bv};
        #pragma unroll
        for (int ks = 0; ks < 2; ++ks) {
            v8h af = *(const v8h*)&u.b.h2f[(mt + l15) * 72 + ks * 32 + fko];
            v8h bf = *(const v8h*)&g_W2aT[(nt + l15) * 64 + ks * 32 + fko];
            tacc = __builtin_amdgcn_mfma_f32_16x16x32_f16(af, bf, tacc, 0, 0, 0);
        }
        int d2 = nt + l15;
        #pragma unroll
        for (int r = 0; r < 4; ++r)
            u.b.tf[(mt + quad * 4 + r) * 72 + d2] = (_Float16)fmaxf(tacc[r], 0.f);
    }
    __syncthreads();

    // h3 = (t*s)@W2b * 256 + b2b; fold mean over k (<KC) and Wl in fp32
    float l0 = 0.f, l1 = 0.f;
    {
        v4f oacc = {0.f, 0.f, 0.f, 0.f};
        #pragma unroll
        for (int ks = 0; ks < 2; ++ks) {
            v8h af = *(const v8h*)&u.b.tf[(mt + l15) * 72 + ks * 32 + fko];
            v8h bf = *(const v8h*)&g_W2bT[(nt + l15) * 64 + ks * 32 + fko];
            oacc = __builtin_amdgcn_mfma_f32_16x16x32_f16(af, bf, oacc, 0, 0, 0);
        }
        int j = nt + l15;
        float bv = b2b[j];
        float wl0 = Wl[j * 2], wl1 = Wl[j * 2 + 1];
        #pragma unroll
        for (int r = 0; r < 4; ++r) {
            int k = mt + quad * 4 + r;
            if (k < KC) {
                float h3v = oacc[r] * TSCI + bv;
                l0 += h3v * wl0; l1 += h3v * wl1;
            }
        }
    }

    float rl0 = blockReduceN(l0, red, 16);
    float rl1 = blockReduceN(l1, red, 16);
    if (tid == 0) {
        float g0 = bl[0] + rl0 * (1.f / KC);
        float g1 = bl[1] + rl1 * (1.f / KC);
        float mm = fmaxf(g0, g1);
        float lse = mm + logf(expf(g0 - mm) + expf(g1 - mm));
        out[2 * g]     = g0 - lse;
        out[2 * g + 1] = g1 - lse;
    }
}

extern "C" void kernel_launch(void* const* d_in, const int* in_sizes, int n_in,
                              void* d_out, int out_size, void* d_ws, size_t ws_size,
                              hipStream_t stream) {
    const float* x    = (const float*)d_in[0];
    const float* W1a  = (const float*)d_in[1];
    const float* b1a  = (const float*)d_in[2];
    const float* W1b  = (const float*)d_in[3];
    const float* b1b  = (const float*)d_in[4];
    const float* Wp   = (const float*)d_in[5];
    const float* bp   = (const float*)d_in[6];
    const float* W2a  = (const float*)d_in[7];
    const float* b2a  = (const float*)d_in[8];
    const float* W2b  = (const float*)d_in[9];
    const float* b2b  = (const float*)d_in[10];
    const float* Wl   = (const float*)d_in[11];
    const float* bl   = (const float*)d_in[12];
    const int*   eidx = (const int*)d_in[13];   // [2, E] int32
    float* out = (float*)d_out;
    float* ws  = (float*)d_ws;

    zero_ws<<<1, 64, 0, stream>>>(ws);
    kw_conv<<<1, 1024, 0, stream>>>(W1b, Wp, W2a, W2b);
    k1a_sort<<<NG, 512, 0, stream>>>(eidx, eidx + ETOT, x);
    k2_mlp<<<NG * NCH, 512, 0, stream>>>(W1a, b1a, b1b, bp, ws);
    k3_fused<<<NG, 1024, 0, stream>>>(eidx, eidx + ETOT,
                                      b2a, b2b, Wl, bl, out, ws);
    finalize_k<<<1, 64, 0, stream>>>(ws, out);
}